// Round 8
// baseline (512.298 us; speedup 1.0000x reference)
//
#include <hip/hip_runtime.h>
#include <math.h>

#define NT   16384
#define DIM  1024
#define HID  2048
#define NE   16
#define CAP  8192

typedef __attribute__((ext_vector_type(4))) float f32x4;
typedef __attribute__((ext_vector_type(4))) int   i32x4;
typedef __attribute__((ext_vector_type(8))) int   i32x8;
typedef __attribute__((ext_vector_type(2))) long long i64x2;

__device__ __forceinline__ unsigned pk4fp8(float a, float b, float c, float d){
  int lo  = __builtin_amdgcn_cvt_pk_fp8_f32(a, b, 0, false);
  int all = __builtin_amdgcn_cvt_pk_fp8_f32(c, d, lo, true);
  return (unsigned)all;
}
__device__ __forceinline__ unsigned char fp8one(float a){
  return (unsigned char)(__builtin_amdgcn_cvt_pk_fp8_f32(a, a, 0, false) & 0xff);
}
// OCP e4m3fn decode
__device__ __forceinline__ float fp8dec(unsigned b){
  unsigned e = (b >> 3) & 15u, m = b & 7u;
  union { unsigned u; float f; } c;
  if (e) { c.u = ((b & 0x80u) << 24) | ((e + 120u) << 23) | (m << 20); return c.f; }
  float mag = (float)m * 0.001953125f;
  return (b & 0x80u) ? -mag : mag;
}

#define GLOAD16(g, l) __builtin_amdgcn_global_load_lds( \
    (const __attribute__((address_space(1))) void*)(g), \
    (__attribute__((address_space(3))) void*)(l), 16, 0, 0)

// ---- fused: x -> fp8 (plain rows) + router logits/softmax/top2 + importance
__global__ __launch_bounds__(256) void convx_router_kernel(
    const float* __restrict__ x, const float* __restrict__ rw, const float* __restrict__ rb,
    unsigned* __restrict__ x8, int* __restrict__ tki, float* __restrict__ tkw,
    float* __restrict__ importance)
{
  __shared__ float sbuf[2][4][16];
  int tid = threadIdx.x;
  int lane = tid & 63, wid = tid >> 6;
  float W[64];
#pragma unroll
  for (int q=0;q<16;q++)
    *(float4*)(W + q*4) = ((const float4*)rw)[tid*16 + q];
  float rbv = rb[lane & 15];
  float impAcc = 0.f;
  int b0 = lane&1, b1=(lane>>1)&1, b2=(lane>>2)&1, b3=(lane>>3)&1;
#pragma unroll 1
  for (int t=0;t<8;++t){
    int tok = blockIdx.x*8 + t;
    float4 xv = ((const float4*)x)[tok*256 + tid];
    x8[tok*256 + tid] = pk4fp8(xv.x, xv.y, xv.z, xv.w);
    float p[16];
#pragma unroll
    for (int e=0;e<16;e++) p[e] = xv.x * W[e];
#pragma unroll
    for (int e=0;e<16;e++) p[e] += xv.y * W[16+e];
#pragma unroll
    for (int e=0;e<16;e++) p[e] += xv.z * W[32+e];
#pragma unroll
    for (int e=0;e<16;e++) p[e] += xv.w * W[48+e];
    float v8[8];
#pragma unroll
    for (int m=0;m<8;m++){
      float mine = b0 ? p[2*m+1] : p[2*m];
      float oth  = b0 ? p[2*m]   : p[2*m+1];
      v8[m] = mine + __shfl_xor(oth, 1, 64);
    }
    float v4a[4];
#pragma unroll
    for (int m=0;m<4;m++){
      float mine = b1 ? v8[2*m+1] : v8[2*m];
      float oth  = b1 ? v8[2*m]   : v8[2*m+1];
      v4a[m] = mine + __shfl_xor(oth, 2, 64);
    }
    float v2a[2];
#pragma unroll
    for (int m=0;m<2;m++){
      float mine = b2 ? v4a[2*m+1] : v4a[2*m];
      float oth  = b2 ? v4a[2*m]   : v4a[2*m+1];
      v2a[m] = mine + __shfl_xor(oth, 4, 64);
    }
    {
      float mine = b3 ? v2a[1] : v2a[0];
      float oth  = b3 ? v2a[0] : v2a[1];
      float v1 = mine + __shfl_xor(oth, 8, 64);
      v1 += __shfl_xor(v1, 16, 64);
      v1 += __shfl_xor(v1, 32, 64);
      if (lane < 16) sbuf[t&1][wid][lane] = v1;
    }
    __syncthreads();
    if (wid == 0){
      int e = lane & 15;
      float logit = sbuf[t&1][0][e] + sbuf[t&1][1][e] + sbuf[t&1][2][e] + sbuf[t&1][3][e] + rbv;
      float mx = logit;
#pragma unroll
      for (int d=1; d<16; d<<=1) mx = fmaxf(mx, __shfl_xor(mx, d, 64));
      float ex = __expf(logit - mx);
      float s = ex;
#pragma unroll
      for (int d=1; d<16; d<<=1) s += __shfl_xor(s, d, 64);
      float pe = ex / s;
      impAcc += pe;
      float v = pe; int idx = e;
#pragma unroll
      for (int d=1; d<16; d<<=1){
        float ov = __shfl_xor(v, d, 64);
        int   oi = __shfl_xor(idx, d, 64);
        bool bet = (ov > v) || (ov == v && oi < idx);
        v = bet ? ov : v; idx = bet ? oi : idx;
      }
      float vt1 = v; int i1 = idx;
      float pm = (e == i1) ? -1.f : pe;
      v = pm; idx = e;
#pragma unroll
      for (int d=1; d<16; d<<=1){
        float ov = __shfl_xor(v, d, 64);
        int   oi = __shfl_xor(idx, d, 64);
        bool bet = (ov > v) || (ov == v && oi < idx);
        v = bet ? ov : v; idx = bet ? oi : idx;
      }
      if (lane == 0){
        tki[2*tok] = i1; tki[2*tok+1] = idx;
        tkw[2*tok] = vt1; tkw[2*tok+1] = v;
      }
    }
  }
  if (wid == 0 && lane < 16) atomicAdd(&importance[lane], impAcc);
}

// ---------------- w [E][K][N] f32 -> wt8 [E][N][K] fp8 x16 (plain) ----------
__global__ __launch_bounds__(256) void prepw_kernel(const float* __restrict__ w,
                                                    unsigned char* __restrict__ wt8,
                                                    int K, int N, float scale){
  __shared__ float T[64][65];
  int e = blockIdx.z;
  int n0 = blockIdx.x*64, k0 = blockIdx.y*64;
  const float* we = w + (size_t)e*K*N;
  unsigned char* oe = wt8 + (size_t)e*K*N;
  int tid = threadIdx.x;
  int rr = tid >> 4, c4 = tid & 15;
#pragma unroll
  for (int p = 0; p < 4; ++p){
    int r = rr + p*16;
    float4 v = *(const float4*)(we + (size_t)(k0 + r)*N + n0 + c4*4);
    T[r][c4*4+0] = v.x*scale; T[r][c4*4+1] = v.y*scale;
    T[r][c4*4+2] = v.z*scale; T[r][c4*4+3] = v.w*scale;
  }
  __syncthreads();
#pragma unroll
  for (int p = 0; p < 4; ++p){
    int n = rr + p*16;
    unsigned u = pk4fp8(T[c4*4+0][n], T[c4*4+1][n], T[c4*4+2][n], T[c4*4+3][n]);
    *(unsigned*)(oe + (size_t)(n0 + n)*K + k0 + c4*4) = u;
  }
}

// ---------------- per-expert ordered lists (ballot scan) --------------------
__global__ __launch_bounds__(1024) void build_lists_kernel(
    const int* __restrict__ tki, const float* __restrict__ tkw,
    int* __restrict__ list, float* __restrict__ wtok, int* __restrict__ keptArr,
    int* __restrict__ counts)
{
  __shared__ int swsum[16];
  int e = blockIdx.x;
  int tid = threadIdx.x, wid = tid >> 6, lane = tid & 63;
  int base = 0;
  for (int c = 0; c < NT/1024; ++c){
    int t = c*1024 + tid;
    int i1 = tki[2*t], i2 = tki[2*t+1];
    bool m = (i1==e) || (i2==e);
    unsigned long long bal = __ballot(m);
    int inw = __popcll(bal & ((1ull << lane) - 1ull));
    if (lane == 0) swsum[wid] = __popcll(bal);
    __syncthreads();
    int pre = 0, tot = 0;
#pragma unroll
    for (int w = 0; w < 16; ++w){
      int v = swsum[w];
      tot += v;
      if (w < wid) pre += v;
    }
    int rank = base + pre + inw;
    if (m && rank < CAP){
      list[e*CAP + rank] = t;
      wtok[e*CAP + rank] = (i1==e) ? tkw[2*t] : -tkw[2*t+1];
    }
    base += tot;
    __syncthreads();
  }
  if (tid==0){ counts[e] = base; keptArr[e] = min(base, CAP); }
}

// ---------------- aux loss + padded (128) row offsets -----------------------
__global__ void finalize_kernel(const int* __restrict__ counts, const float* __restrict__ importance,
                                const int* __restrict__ keptArr, int* __restrict__ padOff,
                                float* __restrict__ auxOut)
{
  if (threadIdx.x == 0 && blockIdx.x == 0){
    float bal = 0.f, il = 0.f;
    int po = 0;
    padOff[0] = 0;
    for (int e=0;e<16;e++){
      float im = importance[e];
      float cf = (float)counts[e];
      bal += (im * (1.f/NT)) * (cf * (1.f/NT));
      il  += im*im;
      po  += ((keptArr[e] + 127) >> 7) << 7;
      padOff[e+1] = po;
    }
    auxOut[0] = bal * 16.f + il * (1.f/16.f);
  }
}

// ===== 128x128 MX-fp8 GEMM (16x16x128 scaled MFMA) =========================
// Single 32KB LDS buffer (A 16K + B 16K), 2-barrier loop, 3-4 blocks/CU for
// cross-block overlap (m114). Conflict-free layout per 16-row block (2KB):
// chunk (row r, unit u) at (u&1)*1024 + ((u>>1)*2 + (r>>3))*128 + (r&7)*16
// -> each 8-lane b128 read group tiles one 128B stripe (verified 0 conflicts,
// R7). Frags built via union half-writes (no shufflevector movs). Staged via
// per-lane SOURCE addressing, linear gload dest (rule 21).
// Scales: A x1 (127), B x2^-4 (123).

#define SETUP_PTRS(SRC_A_EXPR, SRC_B_EXPR) \
  const unsigned char* pA[4]; const unsigned char* pB[4]; \
  _Pragma("unroll") \
  for (int l=0; l<4; ++l){ \
    int g = l*256 + tid; \
    int mb = g>>7; \
    int KBb = (g>>6)&1; \
    int stripe = (g>>3)&7; \
    int pos = g&7; \
    int row = mb*16 + (stripe&1)*8 + pos; \
    int koff = ((((stripe>>1)<<1) | KBb) << 4); \
    pA[l] = (SRC_A_EXPR) + koff; \
    pB[l] = (SRC_B_EXPR) + koff; \
  }

#define STAGE8() do{ \
  GLOAD16(pA[0], lds + tid*16); \
  GLOAD16(pA[1], lds + 4096 + tid*16); \
  GLOAD16(pA[2], lds + 8192 + tid*16); \
  GLOAD16(pA[3], lds + 12288 + tid*16); \
  GLOAD16(pB[0], lds + 16384 + tid*16); \
  GLOAD16(pB[1], lds + 20480 + tid*16); \
  GLOAD16(pB[2], lds + 24576 + tid*16); \
  GLOAD16(pB[3], lds + 28672 + tid*16); \
  pA[0]+=128; pA[1]+=128; pA[2]+=128; pA[3]+=128; \
  pB[0]+=128; pB[1]+=128; pB[2]+=128; pB[3]+=128; }while(0)

#define RDFRAG(dst, base) do{ \
  union { i32x8 v; i32x4 h[2]; } _u; \
  _u.h[0] = *(const i32x4*)(base); \
  _u.h[1] = *(const i32x4*)((base) + 1024); \
  dst = _u.v; }while(0)

#define KLOOP(NT_) \
  for (int t = 0; t < (NT_); ++t){ \
    STAGE8(); \
    asm volatile("s_waitcnt vmcnt(0)" ::: "memory"); \
    __builtin_amdgcn_s_barrier(); \
    i32x8 bfr[4], afr[4]; \
    _Pragma("unroll") \
    for (int nj=0;nj<4;++nj) RDFRAG(bfr[nj], lds + 16384 + (wc*4+nj)*2048 + roff); \
    _Pragma("unroll") \
    for (int mi=0;mi<4;++mi) RDFRAG(afr[mi], lds + (wr*4+mi)*2048 + roff); \
    __builtin_amdgcn_s_setprio(1); \
    _Pragma("unroll") \
    for (int mi=0;mi<4;++mi) \
      _Pragma("unroll") \
      for (int nj=0;nj<4;++nj) \
        acc[mi][nj] = __builtin_amdgcn_mfma_scale_f32_16x16x128_f8f6f4( \
            afr[mi], bfr[nj], acc[mi][nj], 0, 0, 0, 127, 0, 123); \
    __builtin_amdgcn_s_setprio(0); \
    __builtin_amdgcn_s_barrier(); \
  }

// ---------------- GEMM1: hid8 = gelu(gather(x8) @ w1t8^T + b1) --------------
__global__ __launch_bounds__(256, 3) void gemm1_kernel(
    const unsigned char* __restrict__ x8, const unsigned char* __restrict__ w1t8,
    const float* __restrict__ b1, const int* __restrict__ list,
    const int* __restrict__ keptArr, const int* __restrict__ padOff,
    unsigned char* __restrict__ hid8)
{
  __shared__ unsigned char lds[32768];   // A 16K @0, B 16K @16K; epilogue reuse
  int e = blockIdx.z;
  int kept = keptArr[e];
  int mt = blockIdx.y;
  if (mt*128 >= kept) return;
  int n0 = blockIdx.x * 128;

  const unsigned char* Wg = w1t8 + (size_t)e*DIM*HID;
  const int* lst = list + e*CAP;
  int tid = threadIdx.x;
  int lane = tid & 63, wv = tid >> 6;
  int wr = wv >> 1, wc = wv & 1;
  int l15 = lane & 15, kq = lane >> 4;
  int roff = kq*256 + ((l15>>3)<<7) + ((l15&7)<<4);

  SETUP_PTRS(x8 + (size_t)lst[min(mt*128 + row, kept-1)]*DIM,
             Wg + (size_t)(n0 + row)*DIM)

  f32x4 acc[4][4];
#pragma unroll
  for (int i=0;i<4;i++)
#pragma unroll
    for (int j=0;j<4;j++) acc[i][j] = (f32x4){0.f,0.f,0.f,0.f};

  KLOOP(DIM/128)   // 8

  // epilogue: bias+gelu -> fp8, LDS repack, coalesced 16B stores
  const float* b1e = b1 + (size_t)e*HID;
#pragma unroll
  for (int i=0;i<4;i++){
#pragma unroll
    for (int j=0;j<4;j++){
      int c = wc*64 + j*16 + l15;
      float bias = b1e[n0 + c];
#pragma unroll
      for (int r=0;r<4;r++){
        int lrow = wr*64 + i*16 + kq*4 + r;
        float v = acc[i][j][r] + bias;
        float s = 1.f/(1.f + __expf(-1.702f*v));   // sigmoid-approx GELU
        lds[lrow*128 + (c ^ ((lrow&7)<<4))] = fp8one(v*s);
      }
    }
  }
  __builtin_amdgcn_s_barrier();
  size_t rowBase = (size_t)padOff[e] + (size_t)mt*128;
#pragma unroll
  for (int w=0; w<4; ++w){
    int idx = w*256 + tid;
    int row = idx >> 3, u = idx & 7;
    *(i64x2*)(hid8 + (rowBase + row)*HID + n0 + u*16) =
        *(const i64x2*)(lds + row*128 + ((u*16) ^ ((row&7)<<4)));
  }
}

// ---------------- GEMM2: outb[k][tok] = fp8( w * (hid8 @ w2t8^T + b2) ) -----
__global__ __launch_bounds__(256, 3) void gemm2_kernel(
    const unsigned char* __restrict__ hid8, const unsigned char* __restrict__ w2t8,
    const float* __restrict__ b2, const int* __restrict__ list,
    const float* __restrict__ wtok, const int* __restrict__ keptArr,
    const int* __restrict__ padOff, unsigned char* __restrict__ outb)
{
  __shared__ unsigned char lds[32768];
  __shared__ int   s_tk[128];
  __shared__ float s_wv[128];
  int e = blockIdx.z;
  int kept = keptArr[e];
  int mt = blockIdx.y;
  if (mt*128 >= kept) return;
  int n0 = blockIdx.x * 128;

  const unsigned char* Wg = w2t8 + (size_t)e*HID*DIM;
  const unsigned char* hb = hid8 + ((size_t)padOff[e] + (size_t)mt*128)*HID;
  const int*   lst = list + e*CAP;
  const float* wt  = wtok + e*CAP;
  int tid = threadIdx.x;
  int lane = tid & 63, wv = tid >> 6;
  int wr = wv >> 1, wc = wv & 1;
  int l15 = lane & 15, kq = lane >> 4;
  int roff = kq*256 + ((l15>>3)<<7) + ((l15&7)<<4);

  if (tid < 128){
    int m = mt*128 + tid;
    if (m < kept){
      float we = wt[m];
      s_tk[tid] = lst[m] | ((we < 0.f) ? (1<<30) : 0);
      s_wv[tid] = fabsf(we);
    } else { s_tk[tid] = -1; s_wv[tid] = 0.f; }
  }

  SETUP_PTRS(hb + (size_t)row*HID,
             Wg + (size_t)(n0 + row)*HID)

  f32x4 acc[4][4];
#pragma unroll
  for (int i=0;i<4;i++)
#pragma unroll
    for (int j=0;j<4;j++) acc[i][j] = (f32x4){0.f,0.f,0.f,0.f};

  KLOOP(HID/128)   // 16

  // epilogue: w*(acc + b2) -> fp8, repack via LDS, 16B stores to outb
  const float* b2e = b2 + (size_t)e*DIM;
#pragma unroll
  for (int i=0;i<4;i++){
#pragma unroll
    for (int r=0;r<4;r++){
      int lrow = wr*64 + i*16 + kq*4 + r;
      float w = s_wv[lrow];
#pragma unroll
      for (int j=0;j<4;j++){
        int c = wc*64 + j*16 + l15;
        float v = (acc[i][j][r] + b2e[n0 + c]) * w;
        lds[lrow*128 + (c ^ ((lrow&7)<<4))] = fp8one(v);
      }
    }
  }
  __builtin_amdgcn_s_barrier();
#pragma unroll
  for (int w=0; w<4; ++w){
    int idx = w*256 + tid;
    int row = idx >> 3, u = idx & 7;
    int tk = s_tk[row];
    if (tk >= 0){
      int tok = tk & 0xffff, k = tk >> 30;
      *(i64x2*)(outb + ((size_t)(k*NT + tok))*DIM + n0 + u*16) =
          *(const i64x2*)(lds + row*128 + ((u*16) ^ ((row&7)<<4)));
    }
  }
}

// ---------------- combine: y = dec(outb[0][t]) + dec(outb[1][t]) ------------
__global__ __launch_bounds__(256) void combine_kernel(const unsigned char* __restrict__ outb,
                                                      float* __restrict__ y)
{
  int wid = threadIdx.x >> 6, lane = threadIdx.x & 63;
  int t = blockIdx.x*4 + wid;
  const uint4 a = *(const uint4*)(outb + (size_t)t*DIM + lane*16);
  const uint4 b = *(const uint4*)(outb + (size_t)(NT + t)*DIM + lane*16);
  float4* yo = (float4*)(y + (size_t)t*DIM + lane*16);
  unsigned ad[4] = {a.x, a.y, a.z, a.w};
  unsigned bd[4] = {b.x, b.y, b.z, b.w};
#pragma unroll
  for (int d=0; d<4; ++d){
    float4 o;
    o.x = fp8dec(ad[d] & 0xff)        + fp8dec(bd[d] & 0xff);
    o.y = fp8dec((ad[d]>>8) & 0xff)   + fp8dec((bd[d]>>8) & 0xff);
    o.z = fp8dec((ad[d]>>16) & 0xff)  + fp8dec((bd[d]>>16) & 0xff);
    o.w = fp8dec((ad[d]>>24) & 0xff)  + fp8dec((bd[d]>>24) & 0xff);
    yo[d] = o;
  }
}

// ---------------- launch ----------------------------------------------------
extern "C" void kernel_launch(void* const* d_in, const int* in_sizes, int n_in,
                              void* d_out, int out_size, void* d_ws, size_t ws_size,
                              hipStream_t stream)
{
  (void)in_sizes; (void)n_in; (void)ws_size; (void)out_size;
  const float* x  = (const float*)d_in[0];
  const float* rw = (const float*)d_in[1];
  const float* rb = (const float*)d_in[2];
  const float* w1 = (const float*)d_in[3];
  const float* b1 = (const float*)d_in[4];
  const float* w2 = (const float*)d_in[5];
  const float* b2 = (const float*)d_in[6];
  float* y = (float*)d_out;

  char* ws = (char*)d_ws;
  int*   counts = (int*)(ws + 0);
  int*   kept   = (int*)(ws + 64);
  float* imp    = (float*)(ws + 128);
  int*   padoff = (int*)(ws + 192);
  int*   list   = (int*)(ws + 0x1000);     // 512 KiB
  float* wtok   = (float*)(ws + 0x81000);  // 512 KiB
  int*   tki    = (int*)(ws + 0x101000);   // 128 KiB
  float* tkw    = (float*)(ws + 0x121000); // 128 KiB
  unsigned char* wt8  = (unsigned char*)(ws + 0x180000);   // 32 MiB (w1 then w2)
  unsigned char* hid8 = (unsigned char*)(ws + 0x2180000);  // 68 MiB (34816 x 2048)
  unsigned char* big  = (unsigned char*)(ws + 0x6580000);  // 32 MiB: x8 then outb
  unsigned char* x8   = big;                               // 16 MiB, dead after gemm1
  unsigned char* outb = big;                               // 32 MiB, overlays x8
  // total = 0x8580000 = 139.9 MiB

  hipMemsetAsync(ws, 0, 4096, stream);

  convx_router_kernel<<<NT/8, 256, 0, stream>>>(x, rw, rb, (unsigned*)x8, tki, tkw, imp);
  build_lists_kernel<<<16, 1024, 0, stream>>>(tki, tkw, list, wtok, kept, counts);
  finalize_kernel<<<1, 64, 0, stream>>>(counts, imp, kept, padoff, y + (size_t)NT*DIM);
  prepw_kernel<<<dim3(HID/64, DIM/64, NE), 256, 0, stream>>>(w1, wt8, DIM, HID, 16.f);
  gemm1_kernel<<<dim3(HID/128, CAP/128, NE), 256, 0, stream>>>(x8, wt8, b1, list, kept, padoff, hid8);
  // x8 now dead -> outb takes the region
  hipMemsetAsync(outb, 0, (size_t)2*NT*DIM, stream);
  prepw_kernel<<<dim3(DIM/64, HID/64, NE), 256, 0, stream>>>(w2, wt8, HID, DIM, 16.f);
  gemm2_kernel<<<dim3(DIM/128, CAP/128, NE), 256, 0, stream>>>(hid8, wt8, b2, list, wtok, kept, padoff, outb);
  combine_kernel<<<NT/4, 256, 0, stream>>>(outb, y);
}

// Round 9
// 510.750 us; speedup vs baseline: 1.0030x; 1.0030x over previous
//
#include <hip/hip_runtime.h>
#include <math.h>

#define NT   16384
#define DIM  1024
#define HID  2048
#define NE   16
#define CAP  8192

typedef __attribute__((ext_vector_type(4))) float f32x4;
typedef __attribute__((ext_vector_type(4))) int   i32x4;
typedef __attribute__((ext_vector_type(8))) int   i32x8;
typedef __attribute__((ext_vector_type(2))) long long i64x2;

__device__ __forceinline__ unsigned pk4fp8(float a, float b, float c, float d){
  int lo  = __builtin_amdgcn_cvt_pk_fp8_f32(a, b, 0, false);
  int all = __builtin_amdgcn_cvt_pk_fp8_f32(c, d, lo, true);
  return (unsigned)all;
}
__device__ __forceinline__ unsigned char fp8one(float a){
  return (unsigned char)(__builtin_amdgcn_cvt_pk_fp8_f32(a, a, 0, false) & 0xff);
}
// OCP e4m3fn decode
__device__ __forceinline__ float fp8dec(unsigned b){
  unsigned e = (b >> 3) & 15u, m = b & 7u;
  union { unsigned u; float f; } c;
  if (e) { c.u = ((b & 0x80u) << 24) | ((e + 120u) << 23) | (m << 20); return c.f; }
  float mag = (float)m * 0.001953125f;
  return (b & 0x80u) ? -mag : mag;
}

#define GLOAD16(g, l) __builtin_amdgcn_global_load_lds( \
    (const __attribute__((address_space(1))) void*)(g), \
    (__attribute__((address_space(3))) void*)(l), 16, 0, 0)

// ---- fused: x -> fp8 (plain rows) + router logits/softmax/top2 + importance
__global__ __launch_bounds__(256) void convx_router_kernel(
    const float* __restrict__ x, const float* __restrict__ rw, const float* __restrict__ rb,
    unsigned* __restrict__ x8, int* __restrict__ tki, float* __restrict__ tkw,
    float* __restrict__ importance)
{
  __shared__ float sbuf[2][4][16];
  int tid = threadIdx.x;
  int lane = tid & 63, wid = tid >> 6;
  float W[64];
#pragma unroll
  for (int q=0;q<16;q++)
    *(float4*)(W + q*4) = ((const float4*)rw)[tid*16 + q];
  float rbv = rb[lane & 15];
  float impAcc = 0.f;
  int b0 = lane&1, b1=(lane>>1)&1, b2=(lane>>2)&1, b3=(lane>>3)&1;
#pragma unroll 1
  for (int t=0;t<8;++t){
    int tok = blockIdx.x*8 + t;
    float4 xv = ((const float4*)x)[tok*256 + tid];
    x8[tok*256 + tid] = pk4fp8(xv.x, xv.y, xv.z, xv.w);
    float p[16];
#pragma unroll
    for (int e=0;e<16;e++) p[e] = xv.x * W[e];
#pragma unroll
    for (int e=0;e<16;e++) p[e] += xv.y * W[16+e];
#pragma unroll
    for (int e=0;e<16;e++) p[e] += xv.z * W[32+e];
#pragma unroll
    for (int e=0;e<16;e++) p[e] += xv.w * W[48+e];
    float v8[8];
#pragma unroll
    for (int m=0;m<8;m++){
      float mine = b0 ? p[2*m+1] : p[2*m];
      float oth  = b0 ? p[2*m]   : p[2*m+1];
      v8[m] = mine + __shfl_xor(oth, 1, 64);
    }
    float v4a[4];
#pragma unroll
    for (int m=0;m<4;m++){
      float mine = b1 ? v8[2*m+1] : v8[2*m];
      float oth  = b1 ? v8[2*m]   : v8[2*m+1];
      v4a[m] = mine + __shfl_xor(oth, 2, 64);
    }
    float v2a[2];
#pragma unroll
    for (int m=0;m<2;m++){
      float mine = b2 ? v4a[2*m+1] : v4a[2*m];
      float oth  = b2 ? v4a[2*m]   : v4a[2*m+1];
      v2a[m] = mine + __shfl_xor(oth, 4, 64);
    }
    {
      float mine = b3 ? v2a[1] : v2a[0];
      float oth  = b3 ? v2a[0] : v2a[1];
      float v1 = mine + __shfl_xor(oth, 8, 64);
      v1 += __shfl_xor(v1, 16, 64);
      v1 += __shfl_xor(v1, 32, 64);
      if (lane < 16) sbuf[t&1][wid][lane] = v1;
    }
    __syncthreads();
    if (wid == 0){
      int e = lane & 15;
      float logit = sbuf[t&1][0][e] + sbuf[t&1][1][e] + sbuf[t&1][2][e] + sbuf[t&1][3][e] + rbv;
      float mx = logit;
#pragma unroll
      for (int d=1; d<16; d<<=1) mx = fmaxf(mx, __shfl_xor(mx, d, 64));
      float ex = __expf(logit - mx);
      float s = ex;
#pragma unroll
      for (int d=1; d<16; d<<=1) s += __shfl_xor(s, d, 64);
      float pe = ex / s;
      impAcc += pe;
      float v = pe; int idx = e;
#pragma unroll
      for (int d=1; d<16; d<<=1){
        float ov = __shfl_xor(v, d, 64);
        int   oi = __shfl_xor(idx, d, 64);
        bool bet = (ov > v) || (ov == v && oi < idx);
        v = bet ? ov : v; idx = bet ? oi : idx;
      }
      float vt1 = v; int i1 = idx;
      float pm = (e == i1) ? -1.f : pe;
      v = pm; idx = e;
#pragma unroll
      for (int d=1; d<16; d<<=1){
        float ov = __shfl_xor(v, d, 64);
        int   oi = __shfl_xor(idx, d, 64);
        bool bet = (ov > v) || (ov == v && oi < idx);
        v = bet ? ov : v; idx = bet ? oi : idx;
      }
      if (lane == 0){
        tki[2*tok] = i1; tki[2*tok+1] = idx;
        tkw[2*tok] = vt1; tkw[2*tok+1] = v;
      }
    }
  }
  if (wid == 0 && lane < 16) atomicAdd(&importance[lane], impAcc);
}

// ---------------- w [E][K][N] f32 -> wt8 [E][N][K] fp8 x16 (plain) ----------
__global__ __launch_bounds__(256) void prepw_kernel(const float* __restrict__ w,
                                                    unsigned char* __restrict__ wt8,
                                                    int K, int N, float scale){
  __shared__ float T[64][65];
  int e = blockIdx.z;
  int n0 = blockIdx.x*64, k0 = blockIdx.y*64;
  const float* we = w + (size_t)e*K*N;
  unsigned char* oe = wt8 + (size_t)e*K*N;
  int tid = threadIdx.x;
  int rr = tid >> 4, c4 = tid & 15;
#pragma unroll
  for (int p = 0; p < 4; ++p){
    int r = rr + p*16;
    float4 v = *(const float4*)(we + (size_t)(k0 + r)*N + n0 + c4*4);
    T[r][c4*4+0] = v.x*scale; T[r][c4*4+1] = v.y*scale;
    T[r][c4*4+2] = v.z*scale; T[r][c4*4+3] = v.w*scale;
  }
  __syncthreads();
#pragma unroll
  for (int p = 0; p < 4; ++p){
    int n = rr + p*16;
    unsigned u = pk4fp8(T[c4*4+0][n], T[c4*4+1][n], T[c4*4+2][n], T[c4*4+3][n]);
    *(unsigned*)(oe + (size_t)(n0 + n)*K + k0 + c4*4) = u;
  }
}

// ---------------- per-expert ordered lists (ballot scan) --------------------
__global__ __launch_bounds__(1024) void build_lists_kernel(
    const int* __restrict__ tki, const float* __restrict__ tkw,
    int* __restrict__ list, float* __restrict__ wtok, int* __restrict__ keptArr,
    int* __restrict__ counts)
{
  __shared__ int swsum[16];
  int e = blockIdx.x;
  int tid = threadIdx.x, wid = tid >> 6, lane = tid & 63;
  int base = 0;
  for (int c = 0; c < NT/1024; ++c){
    int t = c*1024 + tid;
    int i1 = tki[2*t], i2 = tki[2*t+1];
    bool m = (i1==e) || (i2==e);
    unsigned long long bal = __ballot(m);
    int inw = __popcll(bal & ((1ull << lane) - 1ull));
    if (lane == 0) swsum[wid] = __popcll(bal);
    __syncthreads();
    int pre = 0, tot = 0;
#pragma unroll
    for (int w = 0; w < 16; ++w){
      int v = swsum[w];
      tot += v;
      if (w < wid) pre += v;
    }
    int rank = base + pre + inw;
    if (m && rank < CAP){
      list[e*CAP + rank] = t;
      wtok[e*CAP + rank] = (i1==e) ? tkw[2*t] : -tkw[2*t+1];
    }
    base += tot;
    __syncthreads();
  }
  if (tid==0){ counts[e] = base; keptArr[e] = min(base, CAP); }
}

// ---------------- aux loss + padded (128) row offsets -----------------------
__global__ void finalize_kernel(const int* __restrict__ counts, const float* __restrict__ importance,
                                const int* __restrict__ keptArr, int* __restrict__ padOff,
                                float* __restrict__ auxOut)
{
  if (threadIdx.x == 0 && blockIdx.x == 0){
    float bal = 0.f, il = 0.f;
    int po = 0;
    padOff[0] = 0;
    for (int e=0;e<16;e++){
      float im = importance[e];
      float cf = (float)counts[e];
      bal += (im * (1.f/NT)) * (cf * (1.f/NT));
      il  += im*im;
      po  += ((keptArr[e] + 127) >> 7) << 7;
      padOff[e+1] = po;
    }
    auxOut[0] = bal * 16.f + il * (1.f/16.f);
  }
}

// ===== 128x128 MX-fp8 GEMM (16x16x128 scaled MFMA) =========================
// Single 32KB LDS (A 16K @0, B 16K @16K), 2-barrier loop, 3 blocks/CU.
// LDS tile: row-major [128 rows][128B], 16B granule u stored at u^(row&7)
// (the G4 XOR swizzle, HW-proven). Staging: linear dest, source offset
// (u^(row&7))*16 -- a WITHIN-ROW permutation, so global reads stay fully
// coalesced (R8 lesson: cross-row scatter = 4x overfetch). ds_read frag:
// two b128 at row*128 + ((2kq+h)*16 ^ ((l15&7)<<4)); addr1 = addr0^16.
// XCD-aware block swizzle: consecutive logical (e,mt) panels colocate per XCD.
// Scales: A x1 (127), B x2^-4 (123).

#define SETUP_PTRS(SRC_A_EXPR, SRC_B_EXPR) \
  const unsigned char* pA[4]; const unsigned char* pB[4]; \
  _Pragma("unroll") \
  for (int l=0; l<4; ++l){ \
    int g = l*256 + tid; \
    int row = g >> 3; \
    int u = g & 7; \
    int koff = ((u ^ (row & 7)) << 4); \
    pA[l] = (SRC_A_EXPR) + koff; \
    pB[l] = (SRC_B_EXPR) + koff; \
  }

#define STAGE8() do{ \
  GLOAD16(pA[0], lds + tid*16); \
  GLOAD16(pA[1], lds + 4096 + tid*16); \
  GLOAD16(pA[2], lds + 8192 + tid*16); \
  GLOAD16(pA[3], lds + 12288 + tid*16); \
  GLOAD16(pB[0], lds + 16384 + tid*16); \
  GLOAD16(pB[1], lds + 20480 + tid*16); \
  GLOAD16(pB[2], lds + 24576 + tid*16); \
  GLOAD16(pB[3], lds + 28672 + tid*16); \
  pA[0]+=128; pA[1]+=128; pA[2]+=128; pA[3]+=128; \
  pB[0]+=128; pB[1]+=128; pB[2]+=128; pB[3]+=128; }while(0)

#define RDFRAG(dst, base) do{ \
  union { i32x8 v; i32x4 h[2]; } _u; \
  _u.h[0] = *(const i32x4*)(lds + (base) + off0); \
  _u.h[1] = *(const i32x4*)(lds + (base) + off1); \
  dst = _u.v; }while(0)

#define KLOOP(NT_) \
  for (int t = 0; t < (NT_); ++t){ \
    STAGE8(); \
    asm volatile("s_waitcnt vmcnt(0)" ::: "memory"); \
    __builtin_amdgcn_s_barrier(); \
    i32x8 bfr[4], afr[4]; \
    _Pragma("unroll") \
    for (int nj=0;nj<4;++nj) RDFRAG(bfr[nj], 16384 + (wc*64 + nj*16 + l15)*128); \
    _Pragma("unroll") \
    for (int mi=0;mi<4;++mi) RDFRAG(afr[mi], (wr*64 + mi*16 + l15)*128); \
    __builtin_amdgcn_s_setprio(1); \
    _Pragma("unroll") \
    for (int mi=0;mi<4;++mi) \
      _Pragma("unroll") \
      for (int nj=0;nj<4;++nj) \
        acc[mi][nj] = __builtin_amdgcn_mfma_scale_f32_16x16x128_f8f6f4( \
            afr[mi], bfr[nj], acc[mi][nj], 0, 0, 0, 127, 0, 123); \
    __builtin_amdgcn_s_setprio(0); \
    __builtin_amdgcn_s_barrier(); \
  }

// ---------------- GEMM1: hid8 = gelu(gather(x8) @ w1t8^T + b1) --------------
__global__ __launch_bounds__(256, 3) void gemm1_kernel(
    const unsigned char* __restrict__ x8, const unsigned char* __restrict__ w1t8,
    const float* __restrict__ b1, const int* __restrict__ list,
    const int* __restrict__ keptArr, const int* __restrict__ padOff,
    unsigned char* __restrict__ hid8)
{
  __shared__ unsigned char lds[32768];
  // XCD swizzle: grid (16,64,16) = 16384 blocks, cpx = 2048
  int orig = blockIdx.x + 16*(blockIdx.y + 64*blockIdx.z);
  int lg = (orig & 7)*2048 + (orig >> 3);
  int e = lg >> 10;               // / (16*64)
  int rem = lg & 1023;
  int mt = rem >> 4;
  int n0 = (rem & 15) * 128;
  int kept = keptArr[e];
  if (mt*128 >= kept) return;

  const unsigned char* Wg = w1t8 + (size_t)e*DIM*HID;
  const int* lst = list + e*CAP;
  int tid = threadIdx.x;
  int lane = tid & 63, wv = tid >> 6;
  int wr = wv >> 1, wc = wv & 1;
  int l15 = lane & 15, kq = lane >> 4;
  int off0 = (kq << 5) ^ ((l15 & 7) << 4);
  int off1 = off0 ^ 16;

  SETUP_PTRS(x8 + (size_t)lst[min(mt*128 + row, kept-1)]*DIM,
             Wg + (size_t)(n0 + row)*DIM)

  f32x4 acc[4][4];
#pragma unroll
  for (int i=0;i<4;i++)
#pragma unroll
    for (int j=0;j<4;j++) acc[i][j] = (f32x4){0.f,0.f,0.f,0.f};

  KLOOP(DIM/128)   // 8

  // epilogue: bias+gelu -> fp8, LDS repack, coalesced 16B stores
  const float* b1e = b1 + (size_t)e*HID;
#pragma unroll
  for (int i=0;i<4;i++){
#pragma unroll
    for (int j=0;j<4;j++){
      int c = wc*64 + j*16 + l15;
      float bias = b1e[n0 + c];
#pragma unroll
      for (int r=0;r<4;r++){
        int lrow = wr*64 + i*16 + kq*4 + r;
        float v = acc[i][j][r] + bias;
        float s = 1.f/(1.f + __expf(-1.702f*v));   // sigmoid-approx GELU
        lds[lrow*128 + (c ^ ((lrow&7)<<4))] = fp8one(v*s);
      }
    }
  }
  __builtin_amdgcn_s_barrier();
  size_t rowBase = (size_t)padOff[e] + (size_t)mt*128;
#pragma unroll
  for (int w=0; w<4; ++w){
    int idx = w*256 + tid;
    int row = idx >> 3, u = idx & 7;
    *(i64x2*)(hid8 + (rowBase + row)*HID + n0 + u*16) =
        *(const i64x2*)(lds + row*128 + ((u*16) ^ ((row&7)<<4)));
  }
}

// ---------------- GEMM2: outb[k][tok] = fp8( w * (hid8 @ w2t8^T + b2) ) -----
__global__ __launch_bounds__(256, 3) void gemm2_kernel(
    const unsigned char* __restrict__ hid8, const unsigned char* __restrict__ w2t8,
    const float* __restrict__ b2, const int* __restrict__ list,
    const float* __restrict__ wtok, const int* __restrict__ keptArr,
    const int* __restrict__ padOff, unsigned char* __restrict__ outb)
{
  __shared__ unsigned char lds[32768];
  __shared__ int   s_tk[128];
  __shared__ float s_wv[128];
  // XCD swizzle: grid (8,64,16) = 8192 blocks, cpx = 1024
  int orig = blockIdx.x + 8*(blockIdx.y + 64*blockIdx.z);
  int lg = (orig & 7)*1024 + (orig >> 3);
  int e = lg >> 9;                // / (8*64)
  int rem = lg & 511;
  int mt = rem >> 3;
  int n0 = (rem & 7) * 128;
  int kept = keptArr[e];
  if (mt*128 >= kept) return;

  const unsigned char* Wg = w2t8 + (size_t)e*HID*DIM;
  const unsigned char* hb = hid8 + ((size_t)padOff[e] + (size_t)mt*128)*HID;
  const int*   lst = list + e*CAP;
  const float* wt  = wtok + e*CAP;
  int tid = threadIdx.x;
  int lane = tid & 63, wv = tid >> 6;
  int wr = wv >> 1, wc = wv & 1;
  int l15 = lane & 15, kq = lane >> 4;
  int off0 = (kq << 5) ^ ((l15 & 7) << 4);
  int off1 = off0 ^ 16;

  if (tid < 128){
    int m = mt*128 + tid;
    if (m < kept){
      float we = wt[m];
      s_tk[tid] = lst[m] | ((we < 0.f) ? (1<<30) : 0);
      s_wv[tid] = fabsf(we);
    } else { s_tk[tid] = -1; s_wv[tid] = 0.f; }
  }

  SETUP_PTRS(hb + (size_t)row*HID,
             Wg + (size_t)(n0 + row)*HID)

  f32x4 acc[4][4];
#pragma unroll
  for (int i=0;i<4;i++)
#pragma unroll
    for (int j=0;j<4;j++) acc[i][j] = (f32x4){0.f,0.f,0.f,0.f};

  KLOOP(HID/128)   // 16

  // epilogue: w*(acc + b2) -> fp8, repack via LDS, 16B stores to outb
  const float* b2e = b2 + (size_t)e*DIM;
#pragma unroll
  for (int i=0;i<4;i++){
#pragma unroll
    for (int r=0;r<4;r++){
      int lrow = wr*64 + i*16 + kq*4 + r;
      float w = s_wv[lrow];
#pragma unroll
      for (int j=0;j<4;j++){
        int c = wc*64 + j*16 + l15;
        float v = (acc[i][j][r] + b2e[n0 + c]) * w;
        lds[lrow*128 + (c ^ ((lrow&7)<<4))] = fp8one(v);
      }
    }
  }
  __builtin_amdgcn_s_barrier();
#pragma unroll
  for (int w=0; w<4; ++w){
    int idx = w*256 + tid;
    int row = idx >> 3, u = idx & 7;
    int tk = s_tk[row];
    if (tk >= 0){
      int tok = tk & 0xffff, k = tk >> 30;
      *(i64x2*)(outb + ((size_t)(k*NT + tok))*DIM + n0 + u*16) =
          *(const i64x2*)(lds + row*128 + ((u*16) ^ ((row&7)<<4)));
    }
  }
}

// ---------------- combine: y = dec(outb[0][t]) + dec(outb[1][t]) ------------
__global__ __launch_bounds__(256) void combine_kernel(const unsigned char* __restrict__ outb,
                                                      float* __restrict__ y)
{
  int wid = threadIdx.x >> 6, lane = threadIdx.x & 63;
  int t = blockIdx.x*4 + wid;
  const uint4 a = *(const uint4*)(outb + (size_t)t*DIM + lane*16);
  const uint4 b = *(const uint4*)(outb + (size_t)(NT + t)*DIM + lane*16);
  float4* yo = (float4*)(y + (size_t)t*DIM + lane*16);
  unsigned ad[4] = {a.x, a.y, a.z, a.w};
  unsigned bd[4] = {b.x, b.y, b.z, b.w};
#pragma unroll
  for (int d=0; d<4; ++d){
    float4 o;
    o.x = fp8dec(ad[d] & 0xff)        + fp8dec(bd[d] & 0xff);
    o.y = fp8dec((ad[d]>>8) & 0xff)   + fp8dec((bd[d]>>8) & 0xff);
    o.z = fp8dec((ad[d]>>16) & 0xff)  + fp8dec((bd[d]>>16) & 0xff);
    o.w = fp8dec((ad[d]>>24) & 0xff)  + fp8dec((bd[d]>>24) & 0xff);
    yo[d] = o;
  }
}

// ---------------- launch ----------------------------------------------------
extern "C" void kernel_launch(void* const* d_in, const int* in_sizes, int n_in,
                              void* d_out, int out_size, void* d_ws, size_t ws_size,
                              hipStream_t stream)
{
  (void)in_sizes; (void)n_in; (void)ws_size; (void)out_size;
  const float* x  = (const float*)d_in[0];
  const float* rw = (const float*)d_in[1];
  const float* rb = (const float*)d_in[2];
  const float* w1 = (const float*)d_in[3];
  const float* b1 = (const float*)d_in[4];
  const float* w2 = (const float*)d_in[5];
  const float* b2 = (const float*)d_in[6];
  float* y = (float*)d_out;

  char* ws = (char*)d_ws;
  int*   counts = (int*)(ws + 0);
  int*   kept   = (int*)(ws + 64);
  float* imp    = (float*)(ws + 128);
  int*   padoff = (int*)(ws + 192);
  int*   list   = (int*)(ws + 0x1000);     // 512 KiB
  float* wtok   = (float*)(ws + 0x81000);  // 512 KiB
  int*   tki    = (int*)(ws + 0x101000);   // 128 KiB
  float* tkw    = (float*)(ws + 0x121000); // 128 KiB
  unsigned char* wt8  = (unsigned char*)(ws + 0x180000);   // 32 MiB (w1 then w2)
  unsigned char* hid8 = (unsigned char*)(ws + 0x2180000);  // 68 MiB (34816 x 2048)
  unsigned char* big  = (unsigned char*)(ws + 0x6580000);  // 32 MiB: x8 then outb
  unsigned char* x8   = big;                               // 16 MiB, dead after gemm1
  unsigned char* outb = big;                               // 32 MiB, overlays x8
  // total = 0x8580000 = 139.9 MiB

  hipMemsetAsync(ws, 0, 4096, stream);

  convx_router_kernel<<<NT/8, 256, 0, stream>>>(x, rw, rb, (unsigned*)x8, tki, tkw, imp);
  build_lists_kernel<<<16, 1024, 0, stream>>>(tki, tkw, list, wtok, kept, counts);
  finalize_kernel<<<1, 64, 0, stream>>>(counts, imp, kept, padoff, y + (size_t)NT*DIM);
  prepw_kernel<<<dim3(HID/64, DIM/64, NE), 256, 0, stream>>>(w1, wt8, DIM, HID, 16.f);
  gemm1_kernel<<<dim3(HID/128, CAP/128, NE), 256, 0, stream>>>(x8, wt8, b1, list, kept, padoff, hid8);
  // x8 now dead -> outb takes the region
  hipMemsetAsync(outb, 0, (size_t)2*NT*DIM, stream);
  prepw_kernel<<<dim3(DIM/64, HID/64, NE), 256, 0, stream>>>(w2, wt8, HID, DIM, 16.f);
  gemm2_kernel<<<dim3(DIM/128, CAP/128, NE), 256, 0, stream>>>(hid8, wt8, b2, list, wtok, kept, padoff, outb);
  combine_kernel<<<NT/4, 256, 0, stream>>>(outb, y);
}

// Round 10
// 407.079 us; speedup vs baseline: 1.2585x; 1.2547x over previous
//
#include <hip/hip_runtime.h>
#include <math.h>

#define NT   16384
#define DIM  1024
#define HID  2048
#define NE   16
#define CAP  8192

typedef __attribute__((ext_vector_type(4))) float f32x4;
typedef __attribute__((ext_vector_type(4))) int   i32x4;
typedef __attribute__((ext_vector_type(8))) int   i32x8;
typedef __attribute__((ext_vector_type(2))) long long i64x2;

__device__ __forceinline__ unsigned pk4fp8(float a, float b, float c, float d){
  int lo  = __builtin_amdgcn_cvt_pk_fp8_f32(a, b, 0, false);
  int all = __builtin_amdgcn_cvt_pk_fp8_f32(c, d, lo, true);
  return (unsigned)all;
}
__device__ __forceinline__ unsigned char fp8one(float a){
  return (unsigned char)(__builtin_amdgcn_cvt_pk_fp8_f32(a, a, 0, false) & 0xff);
}
// OCP e4m3fn decode
__device__ __forceinline__ float fp8dec(unsigned b){
  unsigned e = (b >> 3) & 15u, m = b & 7u;
  union { unsigned u; float f; } c;
  if (e) { c.u = ((b & 0x80u) << 24) | ((e + 120u) << 23) | (m << 20); return c.f; }
  float mag = (float)m * 0.001953125f;
  return (b & 0x80u) ? -mag : mag;
}

#define GLOAD16(g, l) __builtin_amdgcn_global_load_lds( \
    (const __attribute__((address_space(1))) void*)(g), \
    (__attribute__((address_space(3))) void*)(l), 16, 0, 0)

// ---- fused: x -> fp8 (plain rows) + router logits/softmax/top2 + importance
__global__ __launch_bounds__(256) void convx_router_kernel(
    const float* __restrict__ x, const float* __restrict__ rw, const float* __restrict__ rb,
    unsigned* __restrict__ x8, int* __restrict__ tki, float* __restrict__ tkw,
    float* __restrict__ importance)
{
  __shared__ float sbuf[2][4][16];
  int tid = threadIdx.x;
  int lane = tid & 63, wid = tid >> 6;
  float W[64];
#pragma unroll
  for (int q=0;q<16;q++)
    *(float4*)(W + q*4) = ((const float4*)rw)[tid*16 + q];
  float rbv = rb[lane & 15];
  float impAcc = 0.f;
  int b0 = lane&1, b1=(lane>>1)&1, b2=(lane>>2)&1, b3=(lane>>3)&1;
#pragma unroll 1
  for (int t=0;t<8;++t){
    int tok = blockIdx.x*8 + t;
    float4 xv = ((const float4*)x)[tok*256 + tid];
    x8[tok*256 + tid] = pk4fp8(xv.x, xv.y, xv.z, xv.w);
    float p[16];
#pragma unroll
    for (int e=0;e<16;e++) p[e] = xv.x * W[e];
#pragma unroll
    for (int e=0;e<16;e++) p[e] += xv.y * W[16+e];
#pragma unroll
    for (int e=0;e<16;e++) p[e] += xv.z * W[32+e];
#pragma unroll
    for (int e=0;e<16;e++) p[e] += xv.w * W[48+e];
    float v8[8];
#pragma unroll
    for (int m=0;m<8;m++){
      float mine = b0 ? p[2*m+1] : p[2*m];
      float oth  = b0 ? p[2*m]   : p[2*m+1];
      v8[m] = mine + __shfl_xor(oth, 1, 64);
    }
    float v4a[4];
#pragma unroll
    for (int m=0;m<4;m++){
      float mine = b1 ? v8[2*m+1] : v8[2*m];
      float oth  = b1 ? v8[2*m]   : v8[2*m+1];
      v4a[m] = mine + __shfl_xor(oth, 2, 64);
    }
    float v2a[2];
#pragma unroll
    for (int m=0;m<2;m++){
      float mine = b2 ? v4a[2*m+1] : v4a[2*m];
      float oth  = b2 ? v4a[2*m]   : v4a[2*m+1];
      v2a[m] = mine + __shfl_xor(oth, 4, 64);
    }
    {
      float mine = b3 ? v2a[1] : v2a[0];
      float oth  = b3 ? v2a[0] : v2a[1];
      float v1 = mine + __shfl_xor(oth, 8, 64);
      v1 += __shfl_xor(v1, 16, 64);
      v1 += __shfl_xor(v1, 32, 64);
      if (lane < 16) sbuf[t&1][wid][lane] = v1;
    }
    __syncthreads();
    if (wid == 0){
      int e = lane & 15;
      float logit = sbuf[t&1][0][e] + sbuf[t&1][1][e] + sbuf[t&1][2][e] + sbuf[t&1][3][e] + rbv;
      float mx = logit;
#pragma unroll
      for (int d=1; d<16; d<<=1) mx = fmaxf(mx, __shfl_xor(mx, d, 64));
      float ex = __expf(logit - mx);
      float s = ex;
#pragma unroll
      for (int d=1; d<16; d<<=1) s += __shfl_xor(s, d, 64);
      float pe = ex / s;
      impAcc += pe;
      float v = pe; int idx = e;
#pragma unroll
      for (int d=1; d<16; d<<=1){
        float ov = __shfl_xor(v, d, 64);
        int   oi = __shfl_xor(idx, d, 64);
        bool bet = (ov > v) || (ov == v && oi < idx);
        v = bet ? ov : v; idx = bet ? oi : idx;
      }
      float vt1 = v; int i1 = idx;
      float pm = (e == i1) ? -1.f : pe;
      v = pm; idx = e;
#pragma unroll
      for (int d=1; d<16; d<<=1){
        float ov = __shfl_xor(v, d, 64);
        int   oi = __shfl_xor(idx, d, 64);
        bool bet = (ov > v) || (ov == v && oi < idx);
        v = bet ? ov : v; idx = bet ? oi : idx;
      }
      if (lane == 0){
        tki[2*tok] = i1; tki[2*tok+1] = idx;
        tkw[2*tok] = vt1; tkw[2*tok+1] = v;
      }
    }
  }
  if (wid == 0 && lane < 16) atomicAdd(&importance[lane], impAcc);
}

// ---------------- w [E][K][N] f32 -> wt8 [E][N][K] fp8 x16 (plain) ----------
__global__ __launch_bounds__(256) void prepw_kernel(const float* __restrict__ w,
                                                    unsigned char* __restrict__ wt8,
                                                    int K, int N, float scale){
  __shared__ float T[64][65];
  int e = blockIdx.z;
  int n0 = blockIdx.x*64, k0 = blockIdx.y*64;
  const float* we = w + (size_t)e*K*N;
  unsigned char* oe = wt8 + (size_t)e*K*N;
  int tid = threadIdx.x;
  int rr = tid >> 4, c4 = tid & 15;
#pragma unroll
  for (int p = 0; p < 4; ++p){
    int r = rr + p*16;
    float4 v = *(const float4*)(we + (size_t)(k0 + r)*N + n0 + c4*4);
    T[r][c4*4+0] = v.x*scale; T[r][c4*4+1] = v.y*scale;
    T[r][c4*4+2] = v.z*scale; T[r][c4*4+3] = v.w*scale;
  }
  __syncthreads();
#pragma unroll
  for (int p = 0; p < 4; ++p){
    int n = rr + p*16;
    unsigned u = pk4fp8(T[c4*4+0][n], T[c4*4+1][n], T[c4*4+2][n], T[c4*4+3][n]);
    *(unsigned*)(oe + (size_t)(n0 + n)*K + k0 + c4*4) = u;
  }
}

// ---------------- per-expert ordered lists (ballot scan) --------------------
__global__ __launch_bounds__(1024) void build_lists_kernel(
    const int* __restrict__ tki, const float* __restrict__ tkw,
    int* __restrict__ list, float* __restrict__ wtok, int* __restrict__ keptArr,
    int* __restrict__ counts)
{
  __shared__ int swsum[16];
  int e = blockIdx.x;
  int tid = threadIdx.x, wid = tid >> 6, lane = tid & 63;
  int base = 0;
  for (int c = 0; c < NT/1024; ++c){
    int t = c*1024 + tid;
    int i1 = tki[2*t], i2 = tki[2*t+1];
    bool m = (i1==e) || (i2==e);
    unsigned long long bal = __ballot(m);
    int inw = __popcll(bal & ((1ull << lane) - 1ull));
    if (lane == 0) swsum[wid] = __popcll(bal);
    __syncthreads();
    int pre = 0, tot = 0;
#pragma unroll
    for (int w = 0; w < 16; ++w){
      int v = swsum[w];
      tot += v;
      if (w < wid) pre += v;
    }
    int rank = base + pre + inw;
    if (m && rank < CAP){
      list[e*CAP + rank] = t;
      wtok[e*CAP + rank] = (i1==e) ? tkw[2*t] : -tkw[2*t+1];
    }
    base += tot;
    __syncthreads();
  }
  if (tid==0){ counts[e] = base; keptArr[e] = min(base, CAP); }
}

// ---------------- aux loss + padded (128) row offsets -----------------------
__global__ void finalize_kernel(const int* __restrict__ counts, const float* __restrict__ importance,
                                const int* __restrict__ keptArr, int* __restrict__ padOff,
                                float* __restrict__ auxOut)
{
  if (threadIdx.x == 0 && blockIdx.x == 0){
    float bal = 0.f, il = 0.f;
    int po = 0;
    padOff[0] = 0;
    for (int e=0;e<16;e++){
      float im = importance[e];
      float cf = (float)counts[e];
      bal += (im * (1.f/NT)) * (cf * (1.f/NT));
      il  += im*im;
      po  += ((keptArr[e] + 127) >> 7) << 7;
      padOff[e+1] = po;
    }
    auxOut[0] = bal * 16.f + il * (1.f/16.f);
  }
}

// ===== 128x128 MX-fp8 GEMM (16x16x128 scaled MFMA), T3/T4 minimum ==========
// Double-buffered 2x32KB LDS. Per K-iter: issue STAGE(t+1 -> other buf) FIRST,
// then 16 ds_read_b128 frags from current buf, setprio(1)+16 MFMA, then ONE
// vmcnt(0)+barrier (loads overlap the whole ds_read+MFMA phase; write target
// never the buffer being read). LDS tile row-major [128][128B], granule u at
// u^(row&7) (within-row source permutation -> staging stays coalesced).
// Frag read: two b128 at row*128 + ((2kq+h)*16 ^ ((l15&7)<<4)).
// Scales: A x1 (127), B x2^-4 (123).

#define SETUP_PTRS(SRC_A_EXPR, SRC_B_EXPR) \
  const unsigned char* pA[4]; const unsigned char* pB[4]; \
  _Pragma("unroll") \
  for (int l=0; l<4; ++l){ \
    int g = l*256 + tid; \
    int row = g >> 3; \
    int u = g & 7; \
    int koff = ((u ^ (row & 7)) << 4); \
    pA[l] = (SRC_A_EXPR) + koff; \
    pB[l] = (SRC_B_EXPR) + koff; \
  }

#define STAGE8(b) do{ \
  GLOAD16(pA[0], lds + (b)*32768 + tid*16); \
  GLOAD16(pA[1], lds + (b)*32768 + 4096 + tid*16); \
  GLOAD16(pA[2], lds + (b)*32768 + 8192 + tid*16); \
  GLOAD16(pA[3], lds + (b)*32768 + 12288 + tid*16); \
  GLOAD16(pB[0], lds + (b)*32768 + 16384 + tid*16); \
  GLOAD16(pB[1], lds + (b)*32768 + 20480 + tid*16); \
  GLOAD16(pB[2], lds + (b)*32768 + 24576 + tid*16); \
  GLOAD16(pB[3], lds + (b)*32768 + 28672 + tid*16); \
  pA[0]+=128; pA[1]+=128; pA[2]+=128; pA[3]+=128; \
  pB[0]+=128; pB[1]+=128; pB[2]+=128; pB[3]+=128; }while(0)

#define RDFRAG(dst, base) do{ \
  union { i32x8 v; i32x4 h[2]; } _u; \
  _u.h[0] = *(const i32x4*)(lds + (base) + off0); \
  _u.h[1] = *(const i32x4*)(lds + (base) + off1); \
  dst = _u.v; }while(0)

#define KLOOP(NT_) \
  STAGE8(0); \
  asm volatile("s_waitcnt vmcnt(0)" ::: "memory"); \
  __builtin_amdgcn_s_barrier(); \
  _Pragma("unroll 2") \
  for (int t = 0; t < (NT_); ++t){ \
    int cur = t & 1; \
    if (t+1 < (NT_)) STAGE8(cur^1); \
    i32x8 bfr[4], afr[4]; \
    _Pragma("unroll") \
    for (int nj=0;nj<4;++nj) RDFRAG(bfr[nj], cur*32768 + 16384 + (wc*64 + nj*16 + l15)*128); \
    _Pragma("unroll") \
    for (int mi=0;mi<4;++mi) RDFRAG(afr[mi], cur*32768 + (wr*64 + mi*16 + l15)*128); \
    __builtin_amdgcn_s_setprio(1); \
    _Pragma("unroll") \
    for (int mi=0;mi<4;++mi) \
      _Pragma("unroll") \
      for (int nj=0;nj<4;++nj) \
        acc[mi][nj] = __builtin_amdgcn_mfma_scale_f32_16x16x128_f8f6f4( \
            afr[mi], bfr[nj], acc[mi][nj], 0, 0, 0, 127, 0, 123); \
    __builtin_amdgcn_s_setprio(0); \
    asm volatile("s_waitcnt vmcnt(0)" ::: "memory"); \
    __builtin_amdgcn_s_barrier(); \
  }

// ---------------- GEMM1: hid8 = gelu(gather(x8) @ w1t8^T + b1) --------------
__global__ __launch_bounds__(256, 2) void gemm1_kernel(
    const unsigned char* __restrict__ x8, const unsigned char* __restrict__ w1t8,
    const float* __restrict__ b1, const int* __restrict__ list,
    const int* __restrict__ keptArr, const int* __restrict__ padOff,
    unsigned char* __restrict__ hid8)
{
  __shared__ unsigned char lds[65536];
  int e = blockIdx.z;
  int kept = keptArr[e];
  int mt = blockIdx.y;
  if (mt*128 >= kept) return;
  int n0 = blockIdx.x * 128;

  const unsigned char* Wg = w1t8 + (size_t)e*DIM*HID;
  const int* lst = list + e*CAP;
  int tid = threadIdx.x;
  int lane = tid & 63, wv = tid >> 6;
  int wr = wv >> 1, wc = wv & 1;
  int l15 = lane & 15, kq = lane >> 4;
  int off0 = (kq << 5) ^ ((l15 & 7) << 4);
  int off1 = off0 ^ 16;

  SETUP_PTRS(x8 + (size_t)lst[min(mt*128 + row, kept-1)]*DIM,
             Wg + (size_t)(n0 + row)*DIM)

  f32x4 acc[4][4];
#pragma unroll
  for (int i=0;i<4;i++)
#pragma unroll
    for (int j=0;j<4;j++) acc[i][j] = (f32x4){0.f,0.f,0.f,0.f};

  KLOOP(DIM/128)   // 8

  // epilogue: bias+gelu -> fp8, LDS repack, coalesced 16B stores
  const float* b1e = b1 + (size_t)e*HID;
#pragma unroll
  for (int i=0;i<4;i++){
#pragma unroll
    for (int j=0;j<4;j++){
      int c = wc*64 + j*16 + l15;
      float bias = b1e[n0 + c];
#pragma unroll
      for (int r=0;r<4;r++){
        int lrow = wr*64 + i*16 + kq*4 + r;
        float v = acc[i][j][r] + bias;
        float s = 1.f/(1.f + __expf(-1.702f*v));   // sigmoid-approx GELU
        lds[lrow*128 + (c ^ ((lrow&7)<<4))] = fp8one(v*s);
      }
    }
  }
  __builtin_amdgcn_s_barrier();
  size_t rowBase = (size_t)padOff[e] + (size_t)mt*128;
#pragma unroll
  for (int w=0; w<4; ++w){
    int idx = w*256 + tid;
    int row = idx >> 3, u = idx & 7;
    *(i64x2*)(hid8 + (rowBase + row)*HID + n0 + u*16) =
        *(const i64x2*)(lds + row*128 + ((u*16) ^ ((row&7)<<4)));
  }
}

// ---------------- GEMM2: outb[k][tok] = fp8( w * (hid8 @ w2t8^T + b2) ) -----
__global__ __launch_bounds__(256, 2) void gemm2_kernel(
    const unsigned char* __restrict__ hid8, const unsigned char* __restrict__ w2t8,
    const float* __restrict__ b2, const int* __restrict__ list,
    const float* __restrict__ wtok, const int* __restrict__ keptArr,
    const int* __restrict__ padOff, unsigned char* __restrict__ outb)
{
  __shared__ unsigned char lds[65536];
  __shared__ int   s_tk[128];
  __shared__ float s_wv[128];
  int e = blockIdx.z;
  int kept = keptArr[e];
  int mt = blockIdx.y;
  if (mt*128 >= kept) return;
  int n0 = blockIdx.x * 128;

  const unsigned char* Wg = w2t8 + (size_t)e*HID*DIM;
  const unsigned char* hb = hid8 + ((size_t)padOff[e] + (size_t)mt*128)*HID;
  const int*   lst = list + e*CAP;
  const float* wt  = wtok + e*CAP;
  int tid = threadIdx.x;
  int lane = tid & 63, wv = tid >> 6;
  int wr = wv >> 1, wc = wv & 1;
  int l15 = lane & 15, kq = lane >> 4;
  int off0 = (kq << 5) ^ ((l15 & 7) << 4);
  int off1 = off0 ^ 16;

  if (tid < 128){
    int m = mt*128 + tid;
    if (m < kept){
      float we = wt[m];
      s_tk[tid] = lst[m] | ((we < 0.f) ? (1<<30) : 0);
      s_wv[tid] = fabsf(we);
    } else { s_tk[tid] = -1; s_wv[tid] = 0.f; }
  }

  SETUP_PTRS(hb + (size_t)row*HID,
             Wg + (size_t)(n0 + row)*HID)

  f32x4 acc[4][4];
#pragma unroll
  for (int i=0;i<4;i++)
#pragma unroll
    for (int j=0;j<4;j++) acc[i][j] = (f32x4){0.f,0.f,0.f,0.f};

  KLOOP(HID/128)   // 16

  // epilogue: w*(acc + b2) -> fp8, repack via LDS, 16B stores to outb
  const float* b2e = b2 + (size_t)e*DIM;
#pragma unroll
  for (int i=0;i<4;i++){
#pragma unroll
    for (int r=0;r<4;r++){
      int lrow = wr*64 + i*16 + kq*4 + r;
      float w = s_wv[lrow];
#pragma unroll
      for (int j=0;j<4;j++){
        int c = wc*64 + j*16 + l15;
        float v = (acc[i][j][r] + b2e[n0 + c]) * w;
        lds[lrow*128 + (c ^ ((lrow&7)<<4))] = fp8one(v);
      }
    }
  }
  __builtin_amdgcn_s_barrier();
#pragma unroll
  for (int w=0; w<4; ++w){
    int idx = w*256 + tid;
    int row = idx >> 3, u = idx & 7;
    int tk = s_tk[row];
    if (tk >= 0){
      int tok = tk & 0xffff, k = tk >> 30;
      *(i64x2*)(outb + ((size_t)(k*NT + tok))*DIM + n0 + u*16) =
          *(const i64x2*)(lds + row*128 + ((u*16) ^ ((row&7)<<4)));
    }
  }
}

// ---------------- combine: y = dec(outb[0][t]) + dec(outb[1][t]) ------------
__global__ __launch_bounds__(256) void combine_kernel(const unsigned char* __restrict__ outb,
                                                      float* __restrict__ y)
{
  int wid = threadIdx.x >> 6, lane = threadIdx.x & 63;
  int t = blockIdx.x*4 + wid;
  const uint4 a = *(const uint4*)(outb + (size_t)t*DIM + lane*16);
  const uint4 b = *(const uint4*)(outb + (size_t)(NT + t)*DIM + lane*16);
  float4* yo = (float4*)(y + (size_t)t*DIM + lane*16);
  unsigned ad[4] = {a.x, a.y, a.z, a.w};
  unsigned bd[4] = {b.x, b.y, b.z, b.w};
#pragma unroll
  for (int d=0; d<4; ++d){
    float4 o;
    o.x = fp8dec(ad[d] & 0xff)        + fp8dec(bd[d] & 0xff);
    o.y = fp8dec((ad[d]>>8) & 0xff)   + fp8dec((bd[d]>>8) & 0xff);
    o.z = fp8dec((ad[d]>>16) & 0xff)  + fp8dec((bd[d]>>16) & 0xff);
    o.w = fp8dec((ad[d]>>24) & 0xff)  + fp8dec((bd[d]>>24) & 0xff);
    yo[d] = o;
  }
}

// ---------------- launch ----------------------------------------------------
extern "C" void kernel_launch(void* const* d_in, const int* in_sizes, int n_in,
                              void* d_out, int out_size, void* d_ws, size_t ws_size,
                              hipStream_t stream)
{
  (void)in_sizes; (void)n_in; (void)ws_size; (void)out_size;
  const float* x  = (const float*)d_in[0];
  const float* rw = (const float*)d_in[1];
  const float* rb = (const float*)d_in[2];
  const float* w1 = (const float*)d_in[3];
  const float* b1 = (const float*)d_in[4];
  const float* w2 = (const float*)d_in[5];
  const float* b2 = (const float*)d_in[6];
  float* y = (float*)d_out;

  char* ws = (char*)d_ws;
  int*   counts = (int*)(ws + 0);
  int*   kept   = (int*)(ws + 64);
  float* imp    = (float*)(ws + 128);
  int*   padoff = (int*)(ws + 192);
  int*   list   = (int*)(ws + 0x1000);     // 512 KiB
  float* wtok   = (float*)(ws + 0x81000);  // 512 KiB
  int*   tki    = (int*)(ws + 0x101000);   // 128 KiB
  float* tkw    = (float*)(ws + 0x121000); // 128 KiB
  unsigned char* wt8  = (unsigned char*)(ws + 0x180000);   // 32 MiB (w1 then w2)
  unsigned char* hid8 = (unsigned char*)(ws + 0x2180000);  // 68 MiB (34816 x 2048)
  unsigned char* big  = (unsigned char*)(ws + 0x6580000);  // 32 MiB: x8 then outb
  unsigned char* x8   = big;                               // 16 MiB, dead after gemm1
  unsigned char* outb = big;                               // 32 MiB, overlays x8
  // total = 0x8580000 = 139.9 MiB

  hipMemsetAsync(ws, 0, 4096, stream);

  convx_router_kernel<<<NT/8, 256, 0, stream>>>(x, rw, rb, (unsigned*)x8, tki, tkw, imp);
  build_lists_kernel<<<16, 1024, 0, stream>>>(tki, tkw, list, wtok, kept, counts);
  finalize_kernel<<<1, 64, 0, stream>>>(counts, imp, kept, padoff, y + (size_t)NT*DIM);
  prepw_kernel<<<dim3(HID/64, DIM/64, NE), 256, 0, stream>>>(w1, wt8, DIM, HID, 16.f);
  gemm1_kernel<<<dim3(HID/128, CAP/128, NE), 256, 0, stream>>>(x8, wt8, b1, list, kept, padoff, hid8);
  // x8 now dead -> outb takes the region
  hipMemsetAsync(outb, 0, (size_t)2*NT*DIM, stream);
  prepw_kernel<<<dim3(DIM/64, HID/64, NE), 256, 0, stream>>>(w2, wt8, HID, DIM, 16.f);
  gemm2_kernel<<<dim3(DIM/128, CAP/128, NE), 256, 0, stream>>>(hid8, wt8, b2, list, wtok, kept, padoff, outb);
  combine_kernel<<<NT/4, 256, 0, stream>>>(outb, y);
}

// Round 11
// 406.674 us; speedup vs baseline: 1.2597x; 1.0010x over previous
//
#include <hip/hip_runtime.h>
#include <math.h>

#define NT   16384
#define DIM  1024
#define HID  2048
#define NE   16
#define CAP  8192

typedef __attribute__((ext_vector_type(4)))  float f32x4;
typedef __attribute__((ext_vector_type(16))) float f32x16;
typedef __attribute__((ext_vector_type(4)))  int   i32x4;
typedef __attribute__((ext_vector_type(8)))  int   i32x8;
typedef __attribute__((ext_vector_type(2)))  long long i64x2;

__device__ __forceinline__ unsigned pk4fp8(float a, float b, float c, float d){
  int lo  = __builtin_amdgcn_cvt_pk_fp8_f32(a, b, 0, false);
  int all = __builtin_amdgcn_cvt_pk_fp8_f32(c, d, lo, true);
  return (unsigned)all;
}
__device__ __forceinline__ unsigned char fp8one(float a){
  return (unsigned char)(__builtin_amdgcn_cvt_pk_fp8_f32(a, a, 0, false) & 0xff);
}
// OCP e4m3fn decode
__device__ __forceinline__ float fp8dec(unsigned b){
  unsigned e = (b >> 3) & 15u, m = b & 7u;
  union { unsigned u; float f; } c;
  if (e) { c.u = ((b & 0x80u) << 24) | ((e + 120u) << 23) | (m << 20); return c.f; }
  float mag = (float)m * 0.001953125f;
  return (b & 0x80u) ? -mag : mag;
}

#define GLOAD16(g, l) __builtin_amdgcn_global_load_lds( \
    (const __attribute__((address_space(1))) void*)(g), \
    (__attribute__((address_space(3))) void*)(l), 16, 0, 0)

// ---- fused: x -> fp8 (plain rows) + router logits/softmax/top2 + importance
__global__ __launch_bounds__(256) void convx_router_kernel(
    const float* __restrict__ x, const float* __restrict__ rw, const float* __restrict__ rb,
    unsigned* __restrict__ x8, int* __restrict__ tki, float* __restrict__ tkw,
    float* __restrict__ importance)
{
  __shared__ float sbuf[2][4][16];
  int tid = threadIdx.x;
  int lane = tid & 63, wid = tid >> 6;
  float W[64];
#pragma unroll
  for (int q=0;q<16;q++)
    *(float4*)(W + q*4) = ((const float4*)rw)[tid*16 + q];
  float rbv = rb[lane & 15];
  float impAcc = 0.f;
  int b0 = lane&1, b1=(lane>>1)&1, b2=(lane>>2)&1, b3=(lane>>3)&1;
#pragma unroll 1
  for (int t=0;t<8;++t){
    int tok = blockIdx.x*8 + t;
    float4 xv = ((const float4*)x)[tok*256 + tid];
    x8[tok*256 + tid] = pk4fp8(xv.x, xv.y, xv.z, xv.w);
    float p[16];
#pragma unroll
    for (int e=0;e<16;e++) p[e] = xv.x * W[e];
#pragma unroll
    for (int e=0;e<16;e++) p[e] += xv.y * W[16+e];
#pragma unroll
    for (int e=0;e<16;e++) p[e] += xv.z * W[32+e];
#pragma unroll
    for (int e=0;e<16;e++) p[e] += xv.w * W[48+e];
    float v8[8];
#pragma unroll
    for (int m=0;m<8;m++){
      float mine = b0 ? p[2*m+1] : p[2*m];
      float oth  = b0 ? p[2*m]   : p[2*m+1];
      v8[m] = mine + __shfl_xor(oth, 1, 64);
    }
    float v4a[4];
#pragma unroll
    for (int m=0;m<4;m++){
      float mine = b1 ? v8[2*m+1] : v8[2*m];
      float oth  = b1 ? v8[2*m]   : v8[2*m+1];
      v4a[m] = mine + __shfl_xor(oth, 2, 64);
    }
    float v2a[2];
#pragma unroll
    for (int m=0;m<2;m++){
      float mine = b2 ? v4a[2*m+1] : v4a[2*m];
      float oth  = b2 ? v4a[2*m]   : v4a[2*m+1];
      v2a[m] = mine + __shfl_xor(oth, 4, 64);
    }
    {
      float mine = b3 ? v2a[1] : v2a[0];
      float oth  = b3 ? v2a[0] : v2a[1];
      float v1 = mine + __shfl_xor(oth, 8, 64);
      v1 += __shfl_xor(v1, 16, 64);
      v1 += __shfl_xor(v1, 32, 64);
      if (lane < 16) sbuf[t&1][wid][lane] = v1;
    }
    __syncthreads();
    if (wid == 0){
      int e = lane & 15;
      float logit = sbuf[t&1][0][e] + sbuf[t&1][1][e] + sbuf[t&1][2][e] + sbuf[t&1][3][e] + rbv;
      float mx = logit;
#pragma unroll
      for (int d=1; d<16; d<<=1) mx = fmaxf(mx, __shfl_xor(mx, d, 64));
      float ex = __expf(logit - mx);
      float s = ex;
#pragma unroll
      for (int d=1; d<16; d<<=1) s += __shfl_xor(s, d, 64);
      float pe = ex / s;
      impAcc += pe;
      float v = pe; int idx = e;
#pragma unroll
      for (int d=1; d<16; d<<=1){
        float ov = __shfl_xor(v, d, 64);
        int   oi = __shfl_xor(idx, d, 64);
        bool bet = (ov > v) || (ov == v && oi < idx);
        v = bet ? ov : v; idx = bet ? oi : idx;
      }
      float vt1 = v; int i1 = idx;
      float pm = (e == i1) ? -1.f : pe;
      v = pm; idx = e;
#pragma unroll
      for (int d=1; d<16; d<<=1){
        float ov = __shfl_xor(v, d, 64);
        int   oi = __shfl_xor(idx, d, 64);
        bool bet = (ov > v) || (ov == v && oi < idx);
        v = bet ? ov : v; idx = bet ? oi : idx;
      }
      if (lane == 0){
        tki[2*tok] = i1; tki[2*tok+1] = idx;
        tkw[2*tok] = vt1; tkw[2*tok+1] = v;
      }
    }
  }
  if (wid == 0 && lane < 16) atomicAdd(&importance[lane], impAcc);
}

// ---------------- w [E][K][N] f32 -> wt8 [E][N][K] fp8 x16 (plain) ----------
__global__ __launch_bounds__(256) void prepw_kernel(const float* __restrict__ w,
                                                    unsigned char* __restrict__ wt8,
                                                    int K, int N, float scale){
  __shared__ float T[64][65];
  int e = blockIdx.z;
  int n0 = blockIdx.x*64, k0 = blockIdx.y*64;
  const float* we = w + (size_t)e*K*N;
  unsigned char* oe = wt8 + (size_t)e*K*N;
  int tid = threadIdx.x;
  int rr = tid >> 4, c4 = tid & 15;
#pragma unroll
  for (int p = 0; p < 4; ++p){
    int r = rr + p*16;
    float4 v = *(const float4*)(we + (size_t)(k0 + r)*N + n0 + c4*4);
    T[r][c4*4+0] = v.x*scale; T[r][c4*4+1] = v.y*scale;
    T[r][c4*4+2] = v.z*scale; T[r][c4*4+3] = v.w*scale;
  }
  __syncthreads();
#pragma unroll
  for (int p = 0; p < 4; ++p){
    int n = rr + p*16;
    unsigned u = pk4fp8(T[c4*4+0][n], T[c4*4+1][n], T[c4*4+2][n], T[c4*4+3][n]);
    *(unsigned*)(oe + (size_t)(n0 + n)*K + k0 + c4*4) = u;
  }
}

// ---------------- per-expert ordered lists (ballot scan) --------------------
__global__ __launch_bounds__(1024) void build_lists_kernel(
    const int* __restrict__ tki, const float* __restrict__ tkw,
    int* __restrict__ list, float* __restrict__ wtok, int* __restrict__ keptArr,
    int* __restrict__ counts)
{
  __shared__ int swsum[16];
  int e = blockIdx.x;
  int tid = threadIdx.x, wid = tid >> 6, lane = tid & 63;
  int base = 0;
  for (int c = 0; c < NT/1024; ++c){
    int t = c*1024 + tid;
    int i1 = tki[2*t], i2 = tki[2*t+1];
    bool m = (i1==e) || (i2==e);
    unsigned long long bal = __ballot(m);
    int inw = __popcll(bal & ((1ull << lane) - 1ull));
    if (lane == 0) swsum[wid] = __popcll(bal);
    __syncthreads();
    int pre = 0, tot = 0;
#pragma unroll
    for (int w = 0; w < 16; ++w){
      int v = swsum[w];
      tot += v;
      if (w < wid) pre += v;
    }
    int rank = base + pre + inw;
    if (m && rank < CAP){
      list[e*CAP + rank] = t;
      wtok[e*CAP + rank] = (i1==e) ? tkw[2*t] : -tkw[2*t+1];
    }
    base += tot;
    __syncthreads();
  }
  if (tid==0){ counts[e] = base; keptArr[e] = min(base, CAP); }
}

// ---------------- aux loss + padded (128) row offsets -----------------------
__global__ void finalize_kernel(const int* __restrict__ counts, const float* __restrict__ importance,
                                const int* __restrict__ keptArr, int* __restrict__ padOff,
                                float* __restrict__ auxOut)
{
  if (threadIdx.x == 0 && blockIdx.x == 0){
    float bal = 0.f, il = 0.f;
    int po = 0;
    padOff[0] = 0;
    for (int e=0;e<16;e++){
      float im = importance[e];
      float cf = (float)counts[e];
      bal += (im * (1.f/NT)) * (cf * (1.f/NT));
      il  += im*im;
      po  += ((keptArr[e] + 127) >> 7) << 7;
      padOff[e+1] = po;
    }
    auxOut[0] = bal * 16.f + il * (1.f/16.f);
  }
}

// ===== 128x128 MX-fp8 GEMM, 32x32x64 scaled MFMA, BK=64 =====================
// Key change vs R10: K-tile = A 8K + B 8K = 16 KB -> double-buffer is only
// 32 KB total -> dbuf stage-early AND 3 blocks/CU now coexist (R6 occupancy +
// R10 pipeline). Per wave (2x2 grid): 2x2 frags of 32x32, acc 4 x f32x16.
// LDS rows 64B, unit u (16B) stored at u^(row&3) (within-row source
// permutation -> staging coalesced; frag reads <=2-way conflicts).
// A-frag: lane l -> row l&31, 32B at k=(l>>5)*32 (analogy to verified
// 16x16x128 mapping). C/D: col=lane&31, row=(q&3)+8*(q>>2)+4*(lane>>5)
// [m74/m101 verified]. Scales: A x1 (127), B x2^-4 (123).

#define SETUP_PTRS(SRC_A_EXPR, SRC_B_EXPR) \
  const unsigned char* pA[2]; const unsigned char* pB[2]; \
  _Pragma("unroll") \
  for (int l=0; l<2; ++l){ \
    int row = l*64 + (tid >> 2); \
    int u = tid & 3; \
    int koff = ((u ^ (row & 3)) << 4); \
    pA[l] = (SRC_A_EXPR) + koff; \
    pB[l] = (SRC_B_EXPR) + koff; \
  }

#define STAGE4(b) do{ \
  GLOAD16(pA[0], lds + (b)*16384 + tid*16); \
  GLOAD16(pA[1], lds + (b)*16384 + 4096 + tid*16); \
  GLOAD16(pB[0], lds + (b)*16384 + 8192 + tid*16); \
  GLOAD16(pB[1], lds + (b)*16384 + 12288 + tid*16); \
  pA[0]+=64; pA[1]+=64; pB[0]+=64; pB[1]+=64; }while(0)

#define RDFRAG(dst, base) do{ \
  union { i32x8 v; i32x4 h[2]; } _u; \
  _u.h[0] = *(const i32x4*)(lds + (base)); \
  _u.h[1] = *(const i32x4*)(lds + ((base) ^ 16)); \
  dst = _u.v; }while(0)

#define KLOOP(NT_) \
  STAGE4(0); \
  asm volatile("s_waitcnt vmcnt(0)" ::: "memory"); \
  __builtin_amdgcn_s_barrier(); \
  _Pragma("unroll 2") \
  for (int t = 0; t < (NT_); ++t){ \
    int cur = t & 1; \
    if (t+1 < (NT_)) STAGE4(cur^1); \
    i32x8 afr[2], bfr[2]; \
    RDFRAG(afr[0], cur*16384 + offA0); \
    RDFRAG(afr[1], cur*16384 + offA1); \
    RDFRAG(bfr[0], cur*16384 + offB0); \
    RDFRAG(bfr[1], cur*16384 + offB1); \
    __builtin_amdgcn_s_setprio(1); \
    acc[0][0] = __builtin_amdgcn_mfma_scale_f32_32x32x64_f8f6f4(afr[0], bfr[0], acc[0][0], 0,0, 0,127, 0,123); \
    acc[0][1] = __builtin_amdgcn_mfma_scale_f32_32x32x64_f8f6f4(afr[0], bfr[1], acc[0][1], 0,0, 0,127, 0,123); \
    acc[1][0] = __builtin_amdgcn_mfma_scale_f32_32x32x64_f8f6f4(afr[1], bfr[0], acc[1][0], 0,0, 0,127, 0,123); \
    acc[1][1] = __builtin_amdgcn_mfma_scale_f32_32x32x64_f8f6f4(afr[1], bfr[1], acc[1][1], 0,0, 0,127, 0,123); \
    __builtin_amdgcn_s_setprio(0); \
    asm volatile("s_waitcnt vmcnt(0)" ::: "memory"); \
    __builtin_amdgcn_s_barrier(); \
  }

// ---------------- GEMM1: hid8 = gelu(gather(x8) @ w1t8^T + b1) --------------
__global__ __launch_bounds__(256, 3) void gemm1_kernel(
    const unsigned char* __restrict__ x8, const unsigned char* __restrict__ w1t8,
    const float* __restrict__ b1, const int* __restrict__ list,
    const int* __restrict__ keptArr, const int* __restrict__ padOff,
    unsigned char* __restrict__ hid8)
{
  __shared__ unsigned char lds[32768];   // 2 x 16KB dbuf; epilogue reuses [0,16K)
  int e = blockIdx.z;
  int kept = keptArr[e];
  int mt = blockIdx.y;
  if (mt*128 >= kept) return;
  int n0 = blockIdx.x * 128;

  const unsigned char* Wg = w1t8 + (size_t)e*DIM*HID;
  const int* lst = list + e*CAP;
  int tid = threadIdx.x;
  int lane = tid & 63, wv = tid >> 6;
  int wr = wv >> 1, wc = wv & 1;
  int l31 = lane & 31, kh = lane >> 5;
  int swz = ((kh*2) ^ (l31 & 3)) << 4;
  int offA0 = (wr*64 + l31)*64 + swz;
  int offA1 = offA0 + 32*64;
  int offB0 = 8192 + (wc*64 + l31)*64 + swz;
  int offB1 = offB0 + 32*64;

  SETUP_PTRS(x8 + (size_t)lst[min(mt*128 + row, kept-1)]*DIM,
             Wg + (size_t)(n0 + row)*DIM)

  f32x16 acc[2][2];
#pragma unroll
  for (int i=0;i<2;i++)
#pragma unroll
    for (int j=0;j<2;j++)
#pragma unroll
      for (int q=0;q<16;q++) acc[i][j][q] = 0.f;

  KLOOP(DIM/64)   // 16

  // epilogue: bias+gelu -> fp8, LDS repack, coalesced 16B stores
  const float* b1e = b1 + (size_t)e*HID;
#pragma unroll
  for (int i=0;i<2;i++){
#pragma unroll
    for (int j=0;j<2;j++){
      int c = wc*64 + j*32 + l31;
      float bias = b1e[n0 + c];
#pragma unroll
      for (int q=0;q<16;q++){
        int lrow = wr*64 + i*32 + (q&3) + 8*(q>>2) + 4*kh;
        float v = acc[i][j][q] + bias;
        float s = 1.f/(1.f + __expf(-1.702f*v));   // sigmoid-approx GELU
        lds[lrow*128 + (c ^ ((lrow&7)<<4))] = fp8one(v*s);
      }
    }
  }
  __builtin_amdgcn_s_barrier();
  size_t rowBase = (size_t)padOff[e] + (size_t)mt*128;
#pragma unroll
  for (int w=0; w<4; ++w){
    int idx = w*256 + tid;
    int row = idx >> 3, u = idx & 7;
    *(i64x2*)(hid8 + (rowBase + row)*HID + n0 + u*16) =
        *(const i64x2*)(lds + row*128 + ((u*16) ^ ((row&7)<<4)));
  }
}

// ---------------- GEMM2: outb[k][tok] = fp8( w * (hid8 @ w2t8^T + b2) ) -----
__global__ __launch_bounds__(256, 3) void gemm2_kernel(
    const unsigned char* __restrict__ hid8, const unsigned char* __restrict__ w2t8,
    const float* __restrict__ b2, const int* __restrict__ list,
    const float* __restrict__ wtok, const int* __restrict__ keptArr,
    const int* __restrict__ padOff, unsigned char* __restrict__ outb)
{
  __shared__ unsigned char lds[32768];
  __shared__ int   s_tk[128];
  __shared__ float s_wv[128];
  int e = blockIdx.z;
  int kept = keptArr[e];
  int mt = blockIdx.y;
  if (mt*128 >= kept) return;
  int n0 = blockIdx.x * 128;

  const unsigned char* Wg = w2t8 + (size_t)e*HID*DIM;
  const unsigned char* hb = hid8 + ((size_t)padOff[e] + (size_t)mt*128)*HID;
  const int*   lst = list + e*CAP;
  const float* wt  = wtok + e*CAP;
  int tid = threadIdx.x;
  int lane = tid & 63, wv = tid >> 6;
  int wr = wv >> 1, wc = wv & 1;
  int l31 = lane & 31, kh = lane >> 5;
  int swz = ((kh*2) ^ (l31 & 3)) << 4;
  int offA0 = (wr*64 + l31)*64 + swz;
  int offA1 = offA0 + 32*64;
  int offB0 = 8192 + (wc*64 + l31)*64 + swz;
  int offB1 = offB0 + 32*64;

  if (tid < 128){
    int m = mt*128 + tid;
    if (m < kept){
      float we = wt[m];
      s_tk[tid] = lst[m] | ((we < 0.f) ? (1<<30) : 0);
      s_wv[tid] = fabsf(we);
    } else { s_tk[tid] = -1; s_wv[tid] = 0.f; }
  }

  SETUP_PTRS(hb + (size_t)row*HID,
             Wg + (size_t)(n0 + row)*HID)

  f32x16 acc[2][2];
#pragma unroll
  for (int i=0;i<2;i++)
#pragma unroll
    for (int j=0;j<2;j++)
#pragma unroll
      for (int q=0;q<16;q++) acc[i][j][q] = 0.f;

  KLOOP(HID/64)   // 32

  // epilogue: w*(acc + b2) -> fp8, repack via LDS, 16B stores to outb
  const float* b2e = b2 + (size_t)e*DIM;
#pragma unroll
  for (int i=0;i<2;i++){
#pragma unroll
    for (int j=0;j<2;j++){
      int c = wc*64 + j*32 + l31;
      float bias = b2e[n0 + c];
#pragma unroll
      for (int q=0;q<16;q++){
        int lrow = wr*64 + i*32 + (q&3) + 8*(q>>2) + 4*kh;
        float v = (acc[i][j][q] + bias) * s_wv[lrow];
        lds[lrow*128 + (c ^ ((lrow&7)<<4))] = fp8one(v);
      }
    }
  }
  __builtin_amdgcn_s_barrier();
#pragma unroll
  for (int w=0; w<4; ++w){
    int idx = w*256 + tid;
    int row = idx >> 3, u = idx & 7;
    int tk = s_tk[row];
    if (tk >= 0){
      int tok = tk & 0xffff, k = tk >> 30;
      *(i64x2*)(outb + ((size_t)(k*NT + tok))*DIM + n0 + u*16) =
          *(const i64x2*)(lds + row*128 + ((u*16) ^ ((row&7)<<4)));
    }
  }
}

// ---------------- combine: y = dec(outb[0][t]) + dec(outb[1][t]) ------------
__global__ __launch_bounds__(256) void combine_kernel(const unsigned char* __restrict__ outb,
                                                      float* __restrict__ y)
{
  int wid = threadIdx.x >> 6, lane = threadIdx.x & 63;
  int t = blockIdx.x*4 + wid;
  const uint4 a = *(const uint4*)(outb + (size_t)t*DIM + lane*16);
  const uint4 b = *(const uint4*)(outb + (size_t)(NT + t)*DIM + lane*16);
  float4* yo = (float4*)(y + (size_t)t*DIM + lane*16);
  unsigned ad[4] = {a.x, a.y, a.z, a.w};
  unsigned bd[4] = {b.x, b.y, b.z, b.w};
#pragma unroll
  for (int d=0; d<4; ++d){
    float4 o;
    o.x = fp8dec(ad[d] & 0xff)        + fp8dec(bd[d] & 0xff);
    o.y = fp8dec((ad[d]>>8) & 0xff)   + fp8dec((bd[d]>>8) & 0xff);
    o.z = fp8dec((ad[d]>>16) & 0xff)  + fp8dec((bd[d]>>16) & 0xff);
    o.w = fp8dec((ad[d]>>24) & 0xff)  + fp8dec((bd[d]>>24) & 0xff);
    yo[d] = o;
  }
}

// ---------------- launch ----------------------------------------------------
extern "C" void kernel_launch(void* const* d_in, const int* in_sizes, int n_in,
                              void* d_out, int out_size, void* d_ws, size_t ws_size,
                              hipStream_t stream)
{
  (void)in_sizes; (void)n_in; (void)ws_size; (void)out_size;
  const float* x  = (const float*)d_in[0];
  const float* rw = (const float*)d_in[1];
  const float* rb = (const float*)d_in[2];
  const float* w1 = (const float*)d_in[3];
  const float* b1 = (const float*)d_in[4];
  const float* w2 = (const float*)d_in[5];
  const float* b2 = (const float*)d_in[6];
  float* y = (float*)d_out;

  char* ws = (char*)d_ws;
  int*   counts = (int*)(ws + 0);
  int*   kept   = (int*)(ws + 64);
  float* imp    = (float*)(ws + 128);
  int*   padoff = (int*)(ws + 192);
  int*   list   = (int*)(ws + 0x1000);     // 512 KiB
  float* wtok   = (float*)(ws + 0x81000);  // 512 KiB
  int*   tki    = (int*)(ws + 0x101000);   // 128 KiB
  float* tkw    = (float*)(ws + 0x121000); // 128 KiB
  unsigned char* wt8  = (unsigned char*)(ws + 0x180000);   // 32 MiB (w1 then w2)
  unsigned char* hid8 = (unsigned char*)(ws + 0x2180000);  // 68 MiB (34816 x 2048)
  unsigned char* big  = (unsigned char*)(ws + 0x6580000);  // 32 MiB: x8 then outb
  unsigned char* x8   = big;                               // 16 MiB, dead after gemm1
  unsigned char* outb = big;                               // 32 MiB, overlays x8
  // total = 0x8580000 = 139.9 MiB

  hipMemsetAsync(ws, 0, 4096, stream);

  convx_router_kernel<<<NT/8, 256, 0, stream>>>(x, rw, rb, (unsigned*)x8, tki, tkw, imp);
  build_lists_kernel<<<16, 1024, 0, stream>>>(tki, tkw, list, wtok, kept, counts);
  finalize_kernel<<<1, 64, 0, stream>>>(counts, imp, kept, padoff, y + (size_t)NT*DIM);
  prepw_kernel<<<dim3(HID/64, DIM/64, NE), 256, 0, stream>>>(w1, wt8, DIM, HID, 16.f);
  gemm1_kernel<<<dim3(HID/128, CAP/128, NE), 256, 0, stream>>>(x8, wt8, b1, list, kept, padoff, hid8);
  // x8 now dead -> outb takes the region
  hipMemsetAsync(outb, 0, (size_t)2*NT*DIM, stream);
  prepw_kernel<<<dim3(DIM/64, HID/64, NE), 256, 0, stream>>>(w2, wt8, HID, DIM, 16.f);
  gemm2_kernel<<<dim3(DIM/128, CAP/128, NE), 256, 0, stream>>>(hid8, wt8, b2, list, wtok, kept, padoff, outb);
  combine_kernel<<<NT/4, 256, 0, stream>>>(outb, y);
}

// Round 12
// 405.199 us; speedup vs baseline: 1.2643x; 1.0036x over previous
//
#include <hip/hip_runtime.h>
#include <math.h>

#define NT   16384
#define DIM  1024
#define HID  2048
#define NE   16
#define CAP  8192

typedef __attribute__((ext_vector_type(4)))  float f32x4;
typedef __attribute__((ext_vector_type(16))) float f32x16;
typedef __attribute__((ext_vector_type(4)))  int   i32x4;
typedef __attribute__((ext_vector_type(8)))  int   i32x8;
typedef __attribute__((ext_vector_type(2)))  long long i64x2;

__device__ __forceinline__ unsigned pk4fp8(float a, float b, float c, float d){
  int lo  = __builtin_amdgcn_cvt_pk_fp8_f32(a, b, 0, false);
  int all = __builtin_amdgcn_cvt_pk_fp8_f32(c, d, lo, true);
  return (unsigned)all;
}
__device__ __forceinline__ unsigned char fp8one(float a){
  return (unsigned char)(__builtin_amdgcn_cvt_pk_fp8_f32(a, a, 0, false) & 0xff);
}
// OCP e4m3fn decode
__device__ __forceinline__ float fp8dec(unsigned b){
  unsigned e = (b >> 3) & 15u, m = b & 7u;
  union { unsigned u; float f; } c;
  if (e) { c.u = ((b & 0x80u) << 24) | ((e + 120u) << 23) | (m << 20); return c.f; }
  float mag = (float)m * 0.001953125f;
  return (b & 0x80u) ? -mag : mag;
}

#define GLOAD16(g, l) __builtin_amdgcn_global_load_lds( \
    (const __attribute__((address_space(1))) void*)(g), \
    (__attribute__((address_space(3))) void*)(l), 16, 0, 0)

// ---- fused: x -> fp8 (plain rows) + router logits/softmax/top2 + importance
__global__ __launch_bounds__(256) void convx_router_kernel(
    const float* __restrict__ x, const float* __restrict__ rw, const float* __restrict__ rb,
    unsigned* __restrict__ x8, int* __restrict__ tki, float* __restrict__ tkw,
    float* __restrict__ importance)
{
  __shared__ float sbuf[2][4][16];
  int tid = threadIdx.x;
  int lane = tid & 63, wid = tid >> 6;
  float W[64];
#pragma unroll
  for (int q=0;q<16;q++)
    *(float4*)(W + q*4) = ((const float4*)rw)[tid*16 + q];
  float rbv = rb[lane & 15];
  float impAcc = 0.f;
  int b0 = lane&1, b1=(lane>>1)&1, b2=(lane>>2)&1, b3=(lane>>3)&1;
#pragma unroll 1
  for (int t=0;t<8;++t){
    int tok = blockIdx.x*8 + t;
    float4 xv = ((const float4*)x)[tok*256 + tid];
    x8[tok*256 + tid] = pk4fp8(xv.x, xv.y, xv.z, xv.w);
    float p[16];
#pragma unroll
    for (int e=0;e<16;e++) p[e] = xv.x * W[e];
#pragma unroll
    for (int e=0;e<16;e++) p[e] += xv.y * W[16+e];
#pragma unroll
    for (int e=0;e<16;e++) p[e] += xv.z * W[32+e];
#pragma unroll
    for (int e=0;e<16;e++) p[e] += xv.w * W[48+e];
    float v8[8];
#pragma unroll
    for (int m=0;m<8;m++){
      float mine = b0 ? p[2*m+1] : p[2*m];
      float oth  = b0 ? p[2*m]   : p[2*m+1];
      v8[m] = mine + __shfl_xor(oth, 1, 64);
    }
    float v4a[4];
#pragma unroll
    for (int m=0;m<4;m++){
      float mine = b1 ? v8[2*m+1] : v8[2*m];
      float oth  = b1 ? v8[2*m]   : v8[2*m+1];
      v4a[m] = mine + __shfl_xor(oth, 2, 64);
    }
    float v2a[2];
#pragma unroll
    for (int m=0;m<2;m++){
      float mine = b2 ? v4a[2*m+1] : v4a[2*m];
      float oth  = b2 ? v4a[2*m]   : v4a[2*m+1];
      v2a[m] = mine + __shfl_xor(oth, 4, 64);
    }
    {
      float mine = b3 ? v2a[1] : v2a[0];
      float oth  = b3 ? v2a[0] : v2a[1];
      float v1 = mine + __shfl_xor(oth, 8, 64);
      v1 += __shfl_xor(v1, 16, 64);
      v1 += __shfl_xor(v1, 32, 64);
      if (lane < 16) sbuf[t&1][wid][lane] = v1;
    }
    __syncthreads();
    if (wid == 0){
      int e = lane & 15;
      float logit = sbuf[t&1][0][e] + sbuf[t&1][1][e] + sbuf[t&1][2][e] + sbuf[t&1][3][e] + rbv;
      float mx = logit;
#pragma unroll
      for (int d=1; d<16; d<<=1) mx = fmaxf(mx, __shfl_xor(mx, d, 64));
      float ex = __expf(logit - mx);
      float s = ex;
#pragma unroll
      for (int d=1; d<16; d<<=1) s += __shfl_xor(s, d, 64);
      float pe = ex / s;
      impAcc += pe;
      float v = pe; int idx = e;
#pragma unroll
      for (int d=1; d<16; d<<=1){
        float ov = __shfl_xor(v, d, 64);
        int   oi = __shfl_xor(idx, d, 64);
        bool bet = (ov > v) || (ov == v && oi < idx);
        v = bet ? ov : v; idx = bet ? oi : idx;
      }
      float vt1 = v; int i1 = idx;
      float pm = (e == i1) ? -1.f : pe;
      v = pm; idx = e;
#pragma unroll
      for (int d=1; d<16; d<<=1){
        float ov = __shfl_xor(v, d, 64);
        int   oi = __shfl_xor(idx, d, 64);
        bool bet = (ov > v) || (ov == v && oi < idx);
        v = bet ? ov : v; idx = bet ? oi : idx;
      }
      if (lane == 0){
        tki[2*tok] = i1; tki[2*tok+1] = idx;
        tkw[2*tok] = vt1; tkw[2*tok+1] = v;
      }
    }
  }
  if (wid == 0 && lane < 16) atomicAdd(&importance[lane], impAcc);
}

// ---------------- w [E][K][N] f32 -> wt8 [E][N][K] fp8 x16 (plain) ----------
__global__ __launch_bounds__(256) void prepw_kernel(const float* __restrict__ w,
                                                    unsigned char* __restrict__ wt8,
                                                    int K, int N, float scale){
  __shared__ float T[64][65];
  int e = blockIdx.z;
  int n0 = blockIdx.x*64, k0 = blockIdx.y*64;
  const float* we = w + (size_t)e*K*N;
  unsigned char* oe = wt8 + (size_t)e*K*N;
  int tid = threadIdx.x;
  int rr = tid >> 4, c4 = tid & 15;
#pragma unroll
  for (int p = 0; p < 4; ++p){
    int r = rr + p*16;
    float4 v = *(const float4*)(we + (size_t)(k0 + r)*N + n0 + c4*4);
    T[r][c4*4+0] = v.x*scale; T[r][c4*4+1] = v.y*scale;
    T[r][c4*4+2] = v.z*scale; T[r][c4*4+3] = v.w*scale;
  }
  __syncthreads();
#pragma unroll
  for (int p = 0; p < 4; ++p){
    int n = rr + p*16;
    unsigned u = pk4fp8(T[c4*4+0][n], T[c4*4+1][n], T[c4*4+2][n], T[c4*4+3][n]);
    *(unsigned*)(oe + (size_t)(n0 + n)*K + k0 + c4*4) = u;
  }
}

// ---------------- per-expert ordered lists (ballot scan) --------------------
__global__ __launch_bounds__(1024) void build_lists_kernel(
    const int* __restrict__ tki, const float* __restrict__ tkw,
    int* __restrict__ list, float* __restrict__ wtok, int* __restrict__ keptArr,
    int* __restrict__ counts)
{
  __shared__ int swsum[16];
  int e = blockIdx.x;
  int tid = threadIdx.x, wid = tid >> 6, lane = tid & 63;
  int base = 0;
  for (int c = 0; c < NT/1024; ++c){
    int t = c*1024 + tid;
    int i1 = tki[2*t], i2 = tki[2*t+1];
    bool m = (i1==e) || (i2==e);
    unsigned long long bal = __ballot(m);
    int inw = __popcll(bal & ((1ull << lane) - 1ull));
    if (lane == 0) swsum[wid] = __popcll(bal);
    __syncthreads();
    int pre = 0, tot = 0;
#pragma unroll
    for (int w = 0; w < 16; ++w){
      int v = swsum[w];
      tot += v;
      if (w < wid) pre += v;
    }
    int rank = base + pre + inw;
    if (m && rank < CAP){
      list[e*CAP + rank] = t;
      wtok[e*CAP + rank] = (i1==e) ? tkw[2*t] : -tkw[2*t+1];
    }
    base += tot;
    __syncthreads();
  }
  if (tid==0){ counts[e] = base; keptArr[e] = min(base, CAP); }
}

// ---------------- aux loss + padded (128) row offsets -----------------------
__global__ void finalize_kernel(const int* __restrict__ counts, const float* __restrict__ importance,
                                const int* __restrict__ keptArr, int* __restrict__ padOff,
                                float* __restrict__ auxOut)
{
  if (threadIdx.x == 0 && blockIdx.x == 0){
    float bal = 0.f, il = 0.f;
    int po = 0;
    padOff[0] = 0;
    for (int e=0;e<16;e++){
      float im = importance[e];
      float cf = (float)counts[e];
      bal += (im * (1.f/NT)) * (cf * (1.f/NT));
      il  += im*im;
      po  += ((keptArr[e] + 127) >> 7) << 7;
      padOff[e+1] = po;
    }
    auxOut[0] = bal * 16.f + il * (1.f/16.f);
  }
}

// ===== 128x128 MX-fp8 GEMM, 32x32x64 scaled MFMA, BK=64 =====================
// R12: TRUE counted pipeline (T3/T4). 3 x 16KB buffers (48KB -> 3 blocks/CU).
// Prologue stages tiles 0,1; iter t stages tile t+2, computes tile t, then
// waits vmcnt(4) (tile t+1 landed -- issued a FULL iteration earlier; loads
// never drain to 0 in steady state). One barrier/iter: all ds_reads of buf t
// are complete (consumed by MFMA pre-barrier) before any wave re-stages it.
// LDS rows 64B, unit u at u^(row&3) (within-row -> staging coalesced).
// A-frag: lane l -> row l&31, 32B at k=(l>>5)*32. C/D: col=lane&31,
// row=(q&3)+8*(q>>2)+4*(lane>>5) [m74/m101]. Scales: A x1(127), B x2^-4(123).

#define SETUP_PTRS(SRC_A_EXPR, SRC_B_EXPR) \
  const unsigned char* pA[2]; const unsigned char* pB[2]; \
  _Pragma("unroll") \
  for (int l=0; l<2; ++l){ \
    int row = l*64 + (tid >> 2); \
    int u = tid & 3; \
    int koff = ((u ^ (row & 3)) << 4); \
    pA[l] = (SRC_A_EXPR) + koff; \
    pB[l] = (SRC_B_EXPR) + koff; \
  }

#define STAGE4(b) do{ \
  GLOAD16(pA[0], lds + (b)*16384 + tid*16); \
  GLOAD16(pA[1], lds + (b)*16384 + 4096 + tid*16); \
  GLOAD16(pB[0], lds + (b)*16384 + 8192 + tid*16); \
  GLOAD16(pB[1], lds + (b)*16384 + 12288 + tid*16); \
  pA[0]+=64; pA[1]+=64; pB[0]+=64; pB[1]+=64; }while(0)

#define RDFRAG(dst, base) do{ \
  union { i32x8 v; i32x4 h[2]; } _u; \
  _u.h[0] = *(const i32x4*)(lds + (base)); \
  _u.h[1] = *(const i32x4*)(lds + ((base) ^ 16)); \
  dst = _u.v; }while(0)

#define KLOOP(NT_) \
  STAGE4(0); \
  STAGE4(1); \
  asm volatile("s_waitcnt vmcnt(4)" ::: "memory"); \
  __builtin_amdgcn_s_barrier(); \
  { int cb = 0, sb = 2; \
    for (int t = 0; t < (NT_); ++t){ \
      if (t+2 < (NT_)) STAGE4(sb); \
      int cbase = cb*16384; \
      i32x8 afr[2], bfr[2]; \
      RDFRAG(afr[0], cbase + offA0); \
      RDFRAG(afr[1], cbase + offA1); \
      RDFRAG(bfr[0], cbase + offB0); \
      RDFRAG(bfr[1], cbase + offB1); \
      __builtin_amdgcn_s_setprio(1); \
      acc[0][0] = __builtin_amdgcn_mfma_scale_f32_32x32x64_f8f6f4(afr[0], bfr[0], acc[0][0], 0,0, 0,127, 0,123); \
      acc[0][1] = __builtin_amdgcn_mfma_scale_f32_32x32x64_f8f6f4(afr[0], bfr[1], acc[0][1], 0,0, 0,127, 0,123); \
      acc[1][0] = __builtin_amdgcn_mfma_scale_f32_32x32x64_f8f6f4(afr[1], bfr[0], acc[1][0], 0,0, 0,127, 0,123); \
      acc[1][1] = __builtin_amdgcn_mfma_scale_f32_32x32x64_f8f6f4(afr[1], bfr[1], acc[1][1], 0,0, 0,127, 0,123); \
      __builtin_amdgcn_s_setprio(0); \
      if (t+1 < (NT_)){ \
        if (t+2 < (NT_)) asm volatile("s_waitcnt vmcnt(4)" ::: "memory"); \
        else             asm volatile("s_waitcnt vmcnt(0)" ::: "memory"); \
      } \
      __builtin_amdgcn_s_barrier(); \
      cb = (cb==2)?0:cb+1; sb = (sb==2)?0:sb+1; \
    } \
  }

// ---------------- GEMM1: hid8 = gelu(gather(x8) @ w1t8^T + b1) --------------
__global__ __launch_bounds__(256, 3) void gemm1_kernel(
    const unsigned char* __restrict__ x8, const unsigned char* __restrict__ w1t8,
    const float* __restrict__ b1, const int* __restrict__ list,
    const int* __restrict__ keptArr, const int* __restrict__ padOff,
    unsigned char* __restrict__ hid8)
{
  __shared__ unsigned char lds[49152];   // 3 x 16KB; epilogue reuses [0,16K)
  int e = blockIdx.z;
  int kept = keptArr[e];
  int mt = blockIdx.y;
  if (mt*128 >= kept) return;
  int n0 = blockIdx.x * 128;

  const unsigned char* Wg = w1t8 + (size_t)e*DIM*HID;
  const int* lst = list + e*CAP;
  int tid = threadIdx.x;
  int lane = tid & 63, wv = tid >> 6;
  int wr = wv >> 1, wc = wv & 1;
  int l31 = lane & 31, kh = lane >> 5;
  int swz = ((kh*2) ^ (l31 & 3)) << 4;
  int offA0 = (wr*64 + l31)*64 + swz;
  int offA1 = offA0 + 32*64;
  int offB0 = 8192 + (wc*64 + l31)*64 + swz;
  int offB1 = offB0 + 32*64;

  SETUP_PTRS(x8 + (size_t)lst[min(mt*128 + row, kept-1)]*DIM,
             Wg + (size_t)(n0 + row)*DIM)

  f32x16 acc[2][2];
#pragma unroll
  for (int i=0;i<2;i++)
#pragma unroll
    for (int j=0;j<2;j++)
#pragma unroll
      for (int q=0;q<16;q++) acc[i][j][q] = 0.f;

  KLOOP(DIM/64)   // 16

  __builtin_amdgcn_s_barrier();   // all K-loop LDS reads done before reuse

  // epilogue: bias+gelu -> fp8, LDS repack, coalesced 16B stores
  const float* b1e = b1 + (size_t)e*HID;
#pragma unroll
  for (int i=0;i<2;i++){
#pragma unroll
    for (int j=0;j<2;j++){
      int c = wc*64 + j*32 + l31;
      float bias = b1e[n0 + c];
#pragma unroll
      for (int q=0;q<16;q++){
        int lrow = wr*64 + i*32 + (q&3) + 8*(q>>2) + 4*kh;
        float v = acc[i][j][q] + bias;
        float s = 1.f/(1.f + __expf(-1.702f*v));   // sigmoid-approx GELU
        lds[lrow*128 + (c ^ ((lrow&7)<<4))] = fp8one(v*s);
      }
    }
  }
  __builtin_amdgcn_s_barrier();
  size_t rowBase = (size_t)padOff[e] + (size_t)mt*128;
#pragma unroll
  for (int w=0; w<4; ++w){
    int idx = w*256 + tid;
    int row = idx >> 3, u = idx & 7;
    *(i64x2*)(hid8 + (rowBase + row)*HID + n0 + u*16) =
        *(const i64x2*)(lds + row*128 + ((u*16) ^ ((row&7)<<4)));
  }
}

// ---------------- GEMM2: outb[k][tok] = fp8( w * (hid8 @ w2t8^T + b2) ) -----
__global__ __launch_bounds__(256, 3) void gemm2_kernel(
    const unsigned char* __restrict__ hid8, const unsigned char* __restrict__ w2t8,
    const float* __restrict__ b2, const int* __restrict__ list,
    const float* __restrict__ wtok, const int* __restrict__ keptArr,
    const int* __restrict__ padOff, unsigned char* __restrict__ outb)
{
  __shared__ unsigned char lds[49152];
  __shared__ int   s_tk[128];
  __shared__ float s_wv[128];
  int e = blockIdx.z;
  int kept = keptArr[e];
  int mt = blockIdx.y;
  if (mt*128 >= kept) return;
  int n0 = blockIdx.x * 128;

  const unsigned char* Wg = w2t8 + (size_t)e*HID*DIM;
  const unsigned char* hb = hid8 + ((size_t)padOff[e] + (size_t)mt*128)*HID;
  const int*   lst = list + e*CAP;
  const float* wt  = wtok + e*CAP;
  int tid = threadIdx.x;
  int lane = tid & 63, wv = tid >> 6;
  int wr = wv >> 1, wc = wv & 1;
  int l31 = lane & 31, kh = lane >> 5;
  int swz = ((kh*2) ^ (l31 & 3)) << 4;
  int offA0 = (wr*64 + l31)*64 + swz;
  int offA1 = offA0 + 32*64;
  int offB0 = 8192 + (wc*64 + l31)*64 + swz;
  int offB1 = offB0 + 32*64;

  if (tid < 128){
    int m = mt*128 + tid;
    if (m < kept){
      float we = wt[m];
      s_tk[tid] = lst[m] | ((we < 0.f) ? (1<<30) : 0);
      s_wv[tid] = fabsf(we);
    } else { s_tk[tid] = -1; s_wv[tid] = 0.f; }
  }

  SETUP_PTRS(hb + (size_t)row*HID,
             Wg + (size_t)(n0 + row)*HID)

  f32x16 acc[2][2];
#pragma unroll
  for (int i=0;i<2;i++)
#pragma unroll
    for (int j=0;j<2;j++)
#pragma unroll
      for (int q=0;q<16;q++) acc[i][j][q] = 0.f;

  KLOOP(HID/64)   // 32

  __builtin_amdgcn_s_barrier();

  // epilogue: w*(acc + b2) -> fp8, repack via LDS, 16B stores to outb
  const float* b2e = b2 + (size_t)e*DIM;
#pragma unroll
  for (int i=0;i<2;i++){
#pragma unroll
    for (int j=0;j<2;j++){
      int c = wc*64 + j*32 + l31;
      float bias = b2e[n0 + c];
#pragma unroll
      for (int q=0;q<16;q++){
        int lrow = wr*64 + i*32 + (q&3) + 8*(q>>2) + 4*kh;
        float v = (acc[i][j][q] + bias) * s_wv[lrow];
        lds[lrow*128 + (c ^ ((lrow&7)<<4))] = fp8one(v);
      }
    }
  }
  __builtin_amdgcn_s_barrier();
#pragma unroll
  for (int w=0; w<4; ++w){
    int idx = w*256 + tid;
    int row = idx >> 3, u = idx & 7;
    int tk = s_tk[row];
    if (tk >= 0){
      int tok = tk & 0xffff, k = tk >> 30;
      *(i64x2*)(outb + ((size_t)(k*NT + tok))*DIM + n0 + u*16) =
          *(const i64x2*)(lds + row*128 + ((u*16) ^ ((row&7)<<4)));
    }
  }
}

// ---------------- combine: y = dec(outb[0][t]) + dec(outb[1][t]) ------------
__global__ __launch_bounds__(256) void combine_kernel(const unsigned char* __restrict__ outb,
                                                      float* __restrict__ y)
{
  int wid = threadIdx.x >> 6, lane = threadIdx.x & 63;
  int t = blockIdx.x*4 + wid;
  const uint4 a = *(const uint4*)(outb + (size_t)t*DIM + lane*16);
  const uint4 b = *(const uint4*)(outb + (size_t)(NT + t)*DIM + lane*16);
  float4* yo = (float4*)(y + (size_t)t*DIM + lane*16);
  unsigned ad[4] = {a.x, a.y, a.z, a.w};
  unsigned bd[4] = {b.x, b.y, b.z, b.w};
#pragma unroll
  for (int d=0; d<4; ++d){
    float4 o;
    o.x = fp8dec(ad[d] & 0xff)        + fp8dec(bd[d] & 0xff);
    o.y = fp8dec((ad[d]>>8) & 0xff)   + fp8dec((bd[d]>>8) & 0xff);
    o.z = fp8dec((ad[d]>>16) & 0xff)  + fp8dec((bd[d]>>16) & 0xff);
    o.w = fp8dec((ad[d]>>24) & 0xff)  + fp8dec((bd[d]>>24) & 0xff);
    yo[d] = o;
  }
}

// ---------------- launch ----------------------------------------------------
extern "C" void kernel_launch(void* const* d_in, const int* in_sizes, int n_in,
                              void* d_out, int out_size, void* d_ws, size_t ws_size,
                              hipStream_t stream)
{
  (void)in_sizes; (void)n_in; (void)ws_size; (void)out_size;
  const float* x  = (const float*)d_in[0];
  const float* rw = (const float*)d_in[1];
  const float* rb = (const float*)d_in[2];
  const float* w1 = (const float*)d_in[3];
  const float* b1 = (const float*)d_in[4];
  const float* w2 = (const float*)d_in[5];
  const float* b2 = (const float*)d_in[6];
  float* y = (float*)d_out;

  char* ws = (char*)d_ws;
  int*   counts = (int*)(ws + 0);
  int*   kept   = (int*)(ws + 64);
  float* imp    = (float*)(ws + 128);
  int*   padoff = (int*)(ws + 192);
  int*   list   = (int*)(ws + 0x1000);     // 512 KiB
  float* wtok   = (float*)(ws + 0x81000);  // 512 KiB
  int*   tki    = (int*)(ws + 0x101000);   // 128 KiB
  float* tkw    = (float*)(ws + 0x121000); // 128 KiB
  unsigned char* wt8  = (unsigned char*)(ws + 0x180000);   // 32 MiB (w1 then w2)
  unsigned char* hid8 = (unsigned char*)(ws + 0x2180000);  // 68 MiB (34816 x 2048)
  unsigned char* big  = (unsigned char*)(ws + 0x6580000);  // 32 MiB: x8 then outb
  unsigned char* x8   = big;                               // 16 MiB, dead after gemm1
  unsigned char* outb = big;                               // 32 MiB, overlays x8
  // total = 0x8580000 = 139.9 MiB

  hipMemsetAsync(ws, 0, 4096, stream);

  convx_router_kernel<<<NT/8, 256, 0, stream>>>(x, rw, rb, (unsigned*)x8, tki, tkw, imp);
  build_lists_kernel<<<16, 1024, 0, stream>>>(tki, tkw, list, wtok, kept, counts);
  finalize_kernel<<<1, 64, 0, stream>>>(counts, imp, kept, padoff, y + (size_t)NT*DIM);
  prepw_kernel<<<dim3(HID/64, DIM/64, NE), 256, 0, stream>>>(w1, wt8, DIM, HID, 16.f);
  gemm1_kernel<<<dim3(HID/128, CAP/128, NE), 256, 0, stream>>>(x8, wt8, b1, list, kept, padoff, hid8);
  // x8 now dead -> outb takes the region
  hipMemsetAsync(outb, 0, (size_t)2*NT*DIM, stream);
  prepw_kernel<<<dim3(DIM/64, HID/64, NE), 256, 0, stream>>>(w2, wt8, HID, DIM, 16.f);
  gemm2_kernel<<<dim3(DIM/128, CAP/128, NE), 256, 0, stream>>>(hid8, wt8, b2, list, wtok, kept, padoff, outb);
  combine_kernel<<<NT/4, 256, 0, stream>>>(outb, y);
}

// Round 13
// 401.121 us; speedup vs baseline: 1.2772x; 1.0102x over previous
//
#include <hip/hip_runtime.h>
#include <math.h>

#define NT   16384
#define DIM  1024
#define HID  2048
#define NE   16
#define CAP  8192

typedef __attribute__((ext_vector_type(4)))  float f32x4;
typedef __attribute__((ext_vector_type(16))) float f32x16;
typedef __attribute__((ext_vector_type(4)))  int   i32x4;
typedef __attribute__((ext_vector_type(8)))  int   i32x8;
typedef __attribute__((ext_vector_type(2)))  long long i64x2;

__device__ __forceinline__ unsigned pk4fp8(float a, float b, float c, float d){
  int lo  = __builtin_amdgcn_cvt_pk_fp8_f32(a, b, 0, false);
  int all = __builtin_amdgcn_cvt_pk_fp8_f32(c, d, lo, true);
  return (unsigned)all;
}
__device__ __forceinline__ unsigned char fp8one(float a){
  return (unsigned char)(__builtin_amdgcn_cvt_pk_fp8_f32(a, a, 0, false) & 0xff);
}
// OCP e4m3fn decode
__device__ __forceinline__ float fp8dec(unsigned b){
  unsigned e = (b >> 3) & 15u, m = b & 7u;
  union { unsigned u; float f; } c;
  if (e) { c.u = ((b & 0x80u) << 24) | ((e + 120u) << 23) | (m << 20); return c.f; }
  float mag = (float)m * 0.001953125f;
  return (b & 0x80u) ? -mag : mag;
}

#define GLOAD16(g, l) __builtin_amdgcn_global_load_lds( \
    (const __attribute__((address_space(1))) void*)(g), \
    (__attribute__((address_space(3))) void*)(l), 16, 0, 0)

// ---- fused: x -> fp8 (plain rows) + router logits/softmax/top2 + importance
__global__ __launch_bounds__(256) void convx_router_kernel(
    const float* __restrict__ x, const float* __restrict__ rw, const float* __restrict__ rb,
    unsigned* __restrict__ x8, int* __restrict__ tki, float* __restrict__ tkw,
    float* __restrict__ importance)
{
  __shared__ float sbuf[2][4][16];
  int tid = threadIdx.x;
  int lane = tid & 63, wid = tid >> 6;
  float W[64];
#pragma unroll
  for (int q=0;q<16;q++)
    *(float4*)(W + q*4) = ((const float4*)rw)[tid*16 + q];
  float rbv = rb[lane & 15];
  float impAcc = 0.f;
  int b0 = lane&1, b1=(lane>>1)&1, b2=(lane>>2)&1, b3=(lane>>3)&1;
#pragma unroll 1
  for (int t=0;t<8;++t){
    int tok = blockIdx.x*8 + t;
    float4 xv = ((const float4*)x)[tok*256 + tid];
    x8[tok*256 + tid] = pk4fp8(xv.x, xv.y, xv.z, xv.w);
    float p[16];
#pragma unroll
    for (int e=0;e<16;e++) p[e] = xv.x * W[e];
#pragma unroll
    for (int e=0;e<16;e++) p[e] += xv.y * W[16+e];
#pragma unroll
    for (int e=0;e<16;e++) p[e] += xv.z * W[32+e];
#pragma unroll
    for (int e=0;e<16;e++) p[e] += xv.w * W[48+e];
    float v8[8];
#pragma unroll
    for (int m=0;m<8;m++){
      float mine = b0 ? p[2*m+1] : p[2*m];
      float oth  = b0 ? p[2*m]   : p[2*m+1];
      v8[m] = mine + __shfl_xor(oth, 1, 64);
    }
    float v4a[4];
#pragma unroll
    for (int m=0;m<4;m++){
      float mine = b1 ? v8[2*m+1] : v8[2*m];
      float oth  = b1 ? v8[2*m]   : v8[2*m+1];
      v4a[m] = mine + __shfl_xor(oth, 2, 64);
    }
    float v2a[2];
#pragma unroll
    for (int m=0;m<2;m++){
      float mine = b2 ? v4a[2*m+1] : v4a[2*m];
      float oth  = b2 ? v4a[2*m]   : v4a[2*m+1];
      v2a[m] = mine + __shfl_xor(oth, 4, 64);
    }
    {
      float mine = b3 ? v2a[1] : v2a[0];
      float oth  = b3 ? v2a[0] : v2a[1];
      float v1 = mine + __shfl_xor(oth, 8, 64);
      v1 += __shfl_xor(v1, 16, 64);
      v1 += __shfl_xor(v1, 32, 64);
      if (lane < 16) sbuf[t&1][wid][lane] = v1;
    }
    __syncthreads();
    if (wid == 0){
      int e = lane & 15;
      float logit = sbuf[t&1][0][e] + sbuf[t&1][1][e] + sbuf[t&1][2][e] + sbuf[t&1][3][e] + rbv;
      float mx = logit;
#pragma unroll
      for (int d=1; d<16; d<<=1) mx = fmaxf(mx, __shfl_xor(mx, d, 64));
      float ex = __expf(logit - mx);
      float s = ex;
#pragma unroll
      for (int d=1; d<16; d<<=1) s += __shfl_xor(s, d, 64);
      float pe = ex / s;
      impAcc += pe;
      float v = pe; int idx = e;
#pragma unroll
      for (int d=1; d<16; d<<=1){
        float ov = __shfl_xor(v, d, 64);
        int   oi = __shfl_xor(idx, d, 64);
        bool bet = (ov > v) || (ov == v && oi < idx);
        v = bet ? ov : v; idx = bet ? oi : idx;
      }
      float vt1 = v; int i1 = idx;
      float pm = (e == i1) ? -1.f : pe;
      v = pm; idx = e;
#pragma unroll
      for (int d=1; d<16; d<<=1){
        float ov = __shfl_xor(v, d, 64);
        int   oi = __shfl_xor(idx, d, 64);
        bool bet = (ov > v) || (ov == v && oi < idx);
        v = bet ? ov : v; idx = bet ? oi : idx;
      }
      if (lane == 0){
        tki[2*tok] = i1; tki[2*tok+1] = idx;
        tkw[2*tok] = vt1; tkw[2*tok+1] = v;
      }
    }
  }
  if (wid == 0 && lane < 16) atomicAdd(&importance[lane], impAcc);
}

// ---------------- w [E][K][N] f32 -> wt8 [E][N][K] fp8 x16 (plain) ----------
__global__ __launch_bounds__(256) void prepw_kernel(const float* __restrict__ w,
                                                    unsigned char* __restrict__ wt8,
                                                    int K, int N, float scale){
  __shared__ float T[64][65];
  int e = blockIdx.z;
  int n0 = blockIdx.x*64, k0 = blockIdx.y*64;
  const float* we = w + (size_t)e*K*N;
  unsigned char* oe = wt8 + (size_t)e*K*N;
  int tid = threadIdx.x;
  int rr = tid >> 4, c4 = tid & 15;
#pragma unroll
  for (int p = 0; p < 4; ++p){
    int r = rr + p*16;
    float4 v = *(const float4*)(we + (size_t)(k0 + r)*N + n0 + c4*4);
    T[r][c4*4+0] = v.x*scale; T[r][c4*4+1] = v.y*scale;
    T[r][c4*4+2] = v.z*scale; T[r][c4*4+3] = v.w*scale;
  }
  __syncthreads();
#pragma unroll
  for (int p = 0; p < 4; ++p){
    int n = rr + p*16;
    unsigned u = pk4fp8(T[c4*4+0][n], T[c4*4+1][n], T[c4*4+2][n], T[c4*4+3][n]);
    *(unsigned*)(oe + (size_t)(n0 + n)*K + k0 + c4*4) = u;
  }
}

// ---------------- per-expert ordered lists (ballot scan) --------------------
__global__ __launch_bounds__(1024) void build_lists_kernel(
    const int* __restrict__ tki, const float* __restrict__ tkw,
    int* __restrict__ list, float* __restrict__ wtok, int* __restrict__ keptArr,
    int* __restrict__ counts)
{
  __shared__ int swsum[16];
  int e = blockIdx.x;
  int tid = threadIdx.x, wid = tid >> 6, lane = tid & 63;
  int base = 0;
  for (int c = 0; c < NT/1024; ++c){
    int t = c*1024 + tid;
    int i1 = tki[2*t], i2 = tki[2*t+1];
    bool m = (i1==e) || (i2==e);
    unsigned long long bal = __ballot(m);
    int inw = __popcll(bal & ((1ull << lane) - 1ull));
    if (lane == 0) swsum[wid] = __popcll(bal);
    __syncthreads();
    int pre = 0, tot = 0;
#pragma unroll
    for (int w = 0; w < 16; ++w){
      int v = swsum[w];
      tot += v;
      if (w < wid) pre += v;
    }
    int rank = base + pre + inw;
    if (m && rank < CAP){
      list[e*CAP + rank] = t;
      wtok[e*CAP + rank] = (i1==e) ? tkw[2*t] : -tkw[2*t+1];
    }
    base += tot;
    __syncthreads();
  }
  if (tid==0){ counts[e] = base; keptArr[e] = min(base, CAP); }
}

// ---------------- aux loss + padded (128) row offsets -----------------------
__global__ void finalize_kernel(const int* __restrict__ counts, const float* __restrict__ importance,
                                const int* __restrict__ keptArr, int* __restrict__ padOff,
                                float* __restrict__ auxOut)
{
  if (threadIdx.x == 0 && blockIdx.x == 0){
    float bal = 0.f, il = 0.f;
    int po = 0;
    padOff[0] = 0;
    for (int e=0;e<16;e++){
      float im = importance[e];
      float cf = (float)counts[e];
      bal += (im * (1.f/NT)) * (cf * (1.f/NT));
      il  += im*im;
      po  += ((keptArr[e] + 127) >> 7) << 7;
      padOff[e+1] = po;
    }
    auxOut[0] = bal * 16.f + il * (1.f/16.f);
  }
}

// ===== 128x256 MX-fp8 GEMM, 32x32x64 scaled MFMA, wave tile 64x128 ==========
// R13: (a) granule perm p(r)=(r>>1)&3 -> every bank-start hit exactly 2x per
// 16-lane group (2-way = free, m136); (b) wave tile 64x128: 2 A-frags x
// 4 B-frags -> 8 MFMA from 6 frag reads (FLOP/LDS-byte 64->128) -> MFMA pipe
// becomes critical path. 3 x 24KB counted buffers (R12 ledger, vmcnt(6)).
// A-frag: lane l -> row l&31, 32B at k=(l>>5)*32. C/D: col=lane&31,
// row=(q&3)+8*(q>>2)+4*(lane>>5) [m74/m101]. Scales: A x1(127), B x2^-4(123).

#define BUFSZ 24576

#define SETUP_PTRS(SRC_A_EXPR, SRC_B_EXPR) \
  const unsigned char* pA[2]; const unsigned char* pB[4]; \
  { int u = tid & 3; \
    _Pragma("unroll") \
    for (int l=0; l<2; ++l){ \
      int row = l*64 + (tid >> 2); \
      int koff = ((u ^ ((row>>1) & 3)) << 4); \
      pA[l] = (SRC_A_EXPR) + koff; \
    } \
    _Pragma("unroll") \
    for (int l=0; l<4; ++l){ \
      int row = l*64 + (tid >> 2); \
      int koff = ((u ^ ((row>>1) & 3)) << 4); \
      pB[l] = (SRC_B_EXPR) + koff; \
    } \
  }

#define STAGE6(b) do{ \
  GLOAD16(pA[0], lds + (b)*BUFSZ + tid*16); \
  GLOAD16(pA[1], lds + (b)*BUFSZ + 4096 + tid*16); \
  GLOAD16(pB[0], lds + (b)*BUFSZ + 8192 + tid*16); \
  GLOAD16(pB[1], lds + (b)*BUFSZ + 12288 + tid*16); \
  GLOAD16(pB[2], lds + (b)*BUFSZ + 16384 + tid*16); \
  GLOAD16(pB[3], lds + (b)*BUFSZ + 20480 + tid*16); \
  pA[0]+=64; pA[1]+=64; pB[0]+=64; pB[1]+=64; pB[2]+=64; pB[3]+=64; }while(0)

#define RDFRAG(dst, base) do{ \
  union { i32x8 v; i32x4 h[2]; } _u; \
  _u.h[0] = *(const i32x4*)(lds + (base)); \
  _u.h[1] = *(const i32x4*)(lds + ((base) ^ 16)); \
  dst = _u.v; }while(0)

#define KLOOP(NT_) \
  STAGE6(0); \
  STAGE6(1); \
  asm volatile("s_waitcnt vmcnt(6)" ::: "memory"); \
  __builtin_amdgcn_s_barrier(); \
  { int cb = 0, sb = 2; \
    for (int t = 0; t < (NT_); ++t){ \
      if (t+2 < (NT_)) STAGE6(sb); \
      int cbase = cb*BUFSZ; \
      i32x8 bfr[4]; \
      RDFRAG(bfr[0], cbase + offB0); \
      RDFRAG(bfr[1], cbase + offB0 + 2048); \
      RDFRAG(bfr[2], cbase + offB0 + 4096); \
      RDFRAG(bfr[3], cbase + offB0 + 6144); \
      _Pragma("unroll") \
      for (int mi=0; mi<2; ++mi){ \
        i32x8 afr; \
        RDFRAG(afr, cbase + offA0 + mi*2048); \
        __builtin_amdgcn_s_setprio(1); \
        acc[mi][0] = __builtin_amdgcn_mfma_scale_f32_32x32x64_f8f6f4(afr, bfr[0], acc[mi][0], 0,0, 0,127, 0,123); \
        acc[mi][1] = __builtin_amdgcn_mfma_scale_f32_32x32x64_f8f6f4(afr, bfr[1], acc[mi][1], 0,0, 0,127, 0,123); \
        acc[mi][2] = __builtin_amdgcn_mfma_scale_f32_32x32x64_f8f6f4(afr, bfr[2], acc[mi][2], 0,0, 0,127, 0,123); \
        acc[mi][3] = __builtin_amdgcn_mfma_scale_f32_32x32x64_f8f6f4(afr, bfr[3], acc[mi][3], 0,0, 0,127, 0,123); \
        __builtin_amdgcn_s_setprio(0); \
      } \
      if (t+1 < (NT_)){ \
        if (t+2 < (NT_)) asm volatile("s_waitcnt vmcnt(6)" ::: "memory"); \
        else             asm volatile("s_waitcnt vmcnt(0)" ::: "memory"); \
      } \
      __builtin_amdgcn_s_barrier(); \
      cb = (cb==2)?0:cb+1; sb = (sb==2)?0:sb+1; \
    } \
  }

// ---------------- GEMM1: hid8 = gelu(gather(x8) @ w1t8^T + b1) --------------
__global__ __launch_bounds__(256, 2) void gemm1_kernel(
    const unsigned char* __restrict__ x8, const unsigned char* __restrict__ w1t8,
    const float* __restrict__ b1, const int* __restrict__ list,
    const int* __restrict__ keptArr, const int* __restrict__ padOff,
    unsigned char* __restrict__ hid8)
{
  __shared__ unsigned char lds[73728];   // 3 x 24KB; epilogue reuses [0,32K)
  int e = blockIdx.z;
  int kept = keptArr[e];
  int mt = blockIdx.y;
  if (mt*128 >= kept) return;
  int n0 = blockIdx.x * 256;

  const unsigned char* Wg = w1t8 + (size_t)e*DIM*HID;
  const int* lst = list + e*CAP;
  int tid = threadIdx.x;
  int lane = tid & 63, wv = tid >> 6;
  int wr = wv >> 1, wc = wv & 1;
  int l31 = lane & 31, kh = lane >> 5;
  int swz = ((kh*2) ^ ((l31>>1) & 3)) << 4;
  int offA0 = (wr*64 + l31)*64 + swz;
  int offB0 = 8192 + (wc*128 + l31)*64 + swz;

  SETUP_PTRS(x8 + (size_t)lst[min(mt*128 + row, kept-1)]*DIM,
             Wg + (size_t)(n0 + row)*DIM)

  f32x16 acc[2][4];
#pragma unroll
  for (int i=0;i<2;i++)
#pragma unroll
    for (int j=0;j<4;j++)
#pragma unroll
      for (int q=0;q<16;q++) acc[i][j][q] = 0.f;

  KLOOP(DIM/64)   // 16

  __builtin_amdgcn_s_barrier();

  // epilogue: bias+gelu -> fp8, LDS repack (128x256), coalesced 16B stores
  const float* b1e = b1 + (size_t)e*HID;
#pragma unroll
  for (int i=0;i<2;i++){
#pragma unroll
    for (int j=0;j<4;j++){
      int c = wc*128 + j*32 + l31;
      float bias = b1e[n0 + c];
#pragma unroll
      for (int q=0;q<16;q++){
        int lrow = wr*64 + i*32 + (q&3) + 8*(q>>2) + 4*kh;
        float v = acc[i][j][q] + bias;
        float s = 1.f/(1.f + __expf(-1.702f*v));   // sigmoid-approx GELU
        lds[lrow*256 + (c ^ ((lrow&7)<<4))] = fp8one(v*s);
      }
    }
  }
  __builtin_amdgcn_s_barrier();
  size_t rowBase = (size_t)padOff[e] + (size_t)mt*128;
#pragma unroll
  for (int w=0; w<8; ++w){
    int idx = w*256 + tid;
    int row = idx >> 4, u = idx & 15;
    *(i64x2*)(hid8 + (rowBase + row)*HID + n0 + u*16) =
        *(const i64x2*)(lds + row*256 + ((u*16) ^ ((row&7)<<4)));
  }
}

// ---------------- GEMM2: outb[k][tok] = fp8( w * (hid8 @ w2t8^T + b2) ) -----
__global__ __launch_bounds__(256, 2) void gemm2_kernel(
    const unsigned char* __restrict__ hid8, const unsigned char* __restrict__ w2t8,
    const float* __restrict__ b2, const int* __restrict__ list,
    const float* __restrict__ wtok, const int* __restrict__ keptArr,
    const int* __restrict__ padOff, unsigned char* __restrict__ outb)
{
  __shared__ unsigned char lds[73728];
  __shared__ int   s_tk[128];
  __shared__ float s_wv[128];
  int e = blockIdx.z;
  int kept = keptArr[e];
  int mt = blockIdx.y;
  if (mt*128 >= kept) return;
  int n0 = blockIdx.x * 256;

  const unsigned char* Wg = w2t8 + (size_t)e*HID*DIM;
  const unsigned char* hb = hid8 + ((size_t)padOff[e] + (size_t)mt*128)*HID;
  const int*   lst = list + e*CAP;
  const float* wt  = wtok + e*CAP;
  int tid = threadIdx.x;
  int lane = tid & 63, wv = tid >> 6;
  int wr = wv >> 1, wc = wv & 1;
  int l31 = lane & 31, kh = lane >> 5;
  int swz = ((kh*2) ^ ((l31>>1) & 3)) << 4;
  int offA0 = (wr*64 + l31)*64 + swz;
  int offB0 = 8192 + (wc*128 + l31)*64 + swz;

  if (tid < 128){
    int m = mt*128 + tid;
    if (m < kept){
      float we = wt[m];
      s_tk[tid] = lst[m] | ((we < 0.f) ? (1<<30) : 0);
      s_wv[tid] = fabsf(we);
    } else { s_tk[tid] = -1; s_wv[tid] = 0.f; }
  }

  SETUP_PTRS(hb + (size_t)row*HID,
             Wg + (size_t)(n0 + row)*HID)

  f32x16 acc[2][4];
#pragma unroll
  for (int i=0;i<2;i++)
#pragma unroll
    for (int j=0;j<4;j++)
#pragma unroll
      for (int q=0;q<16;q++) acc[i][j][q] = 0.f;

  KLOOP(HID/64)   // 32

  __builtin_amdgcn_s_barrier();

  // epilogue: w*(acc + b2) -> fp8, repack via LDS (128x256), 16B stores
  const float* b2e = b2 + (size_t)e*DIM;
#pragma unroll
  for (int i=0;i<2;i++){
#pragma unroll
    for (int j=0;j<4;j++){
      int c = wc*128 + j*32 + l31;
      float bias = b2e[n0 + c];
#pragma unroll
      for (int q=0;q<16;q++){
        int lrow = wr*64 + i*32 + (q&3) + 8*(q>>2) + 4*kh;
        float v = (acc[i][j][q] + bias) * s_wv[lrow];
        lds[lrow*256 + (c ^ ((lrow&7)<<4))] = fp8one(v);
      }
    }
  }
  __builtin_amdgcn_s_barrier();
#pragma unroll
  for (int w=0; w<8; ++w){
    int idx = w*256 + tid;
    int row = idx >> 4, u = idx & 15;
    int tk = s_tk[row];
    if (tk >= 0){
      int tok = tk & 0xffff, k = tk >> 30;
      *(i64x2*)(outb + ((size_t)(k*NT + tok))*DIM + n0 + u*16) =
          *(const i64x2*)(lds + row*256 + ((u*16) ^ ((row&7)<<4)));
    }
  }
}

// ---------------- combine: y = dec(outb[0][t]) + dec(outb[1][t]) ------------
__global__ __launch_bounds__(256) void combine_kernel(const unsigned char* __restrict__ outb,
                                                      float* __restrict__ y)
{
  int wid = threadIdx.x >> 6, lane = threadIdx.x & 63;
  int t = blockIdx.x*4 + wid;
  const uint4 a = *(const uint4*)(outb + (size_t)t*DIM + lane*16);
  const uint4 b = *(const uint4*)(outb + (size_t)(NT + t)*DIM + lane*16);
  float4* yo = (float4*)(y + (size_t)t*DIM + lane*16);
  unsigned ad[4] = {a.x, a.y, a.z, a.w};
  unsigned bd[4] = {b.x, b.y, b.z, b.w};
#pragma unroll
  for (int d=0; d<4; ++d){
    float4 o;
    o.x = fp8dec(ad[d] & 0xff)        + fp8dec(bd[d] & 0xff);
    o.y = fp8dec((ad[d]>>8) & 0xff)   + fp8dec((bd[d]>>8) & 0xff);
    o.z = fp8dec((ad[d]>>16) & 0xff)  + fp8dec((bd[d]>>16) & 0xff);
    o.w = fp8dec((ad[d]>>24) & 0xff)  + fp8dec((bd[d]>>24) & 0xff);
    yo[d] = o;
  }
}

// ---------------- launch ----------------------------------------------------
extern "C" void kernel_launch(void* const* d_in, const int* in_sizes, int n_in,
                              void* d_out, int out_size, void* d_ws, size_t ws_size,
                              hipStream_t stream)
{
  (void)in_sizes; (void)n_in; (void)ws_size; (void)out_size;
  const float* x  = (const float*)d_in[0];
  const float* rw = (const float*)d_in[1];
  const float* rb = (const float*)d_in[2];
  const float* w1 = (const float*)d_in[3];
  const float* b1 = (const float*)d_in[4];
  const float* w2 = (const float*)d_in[5];
  const float* b2 = (const float*)d_in[6];
  float* y = (float*)d_out;

  char* ws = (char*)d_ws;
  int*   counts = (int*)(ws + 0);
  int*   kept   = (int*)(ws + 64);
  float* imp    = (float*)(ws + 128);
  int*   padoff = (int*)(ws + 192);
  int*   list   = (int*)(ws + 0x1000);     // 512 KiB
  float* wtok   = (float*)(ws + 0x81000);  // 512 KiB
  int*   tki    = (int*)(ws + 0x101000);   // 128 KiB
  float* tkw    = (float*)(ws + 0x121000); // 128 KiB
  unsigned char* wt8  = (unsigned char*)(ws + 0x180000);   // 32 MiB (w1 then w2)
  unsigned char* hid8 = (unsigned char*)(ws + 0x2180000);  // 68 MiB (34816 x 2048)
  unsigned char* big  = (unsigned char*)(ws + 0x6580000);  // 32 MiB: x8 then outb
  unsigned char* x8   = big;                               // 16 MiB, dead after gemm1
  unsigned char* outb = big;                               // 32 MiB, overlays x8
  // total = 0x8580000 = 139.9 MiB

  hipMemsetAsync(ws, 0, 4096, stream);

  convx_router_kernel<<<NT/8, 256, 0, stream>>>(x, rw, rb, (unsigned*)x8, tki, tkw, imp);
  build_lists_kernel<<<16, 1024, 0, stream>>>(tki, tkw, list, wtok, kept, counts);
  finalize_kernel<<<1, 64, 0, stream>>>(counts, imp, kept, padoff, y + (size_t)NT*DIM);
  prepw_kernel<<<dim3(HID/64, DIM/64, NE), 256, 0, stream>>>(w1, wt8, DIM, HID, 16.f);
  gemm1_kernel<<<dim3(HID/256, CAP/128, NE), 256, 0, stream>>>(x8, wt8, b1, list, kept, padoff, hid8);
  // x8 now dead -> outb takes the region
  hipMemsetAsync(outb, 0, (size_t)2*NT*DIM, stream);
  prepw_kernel<<<dim3(DIM/64, HID/64, NE), 256, 0, stream>>>(w2, wt8, HID, DIM, 16.f);
  gemm2_kernel<<<dim3(DIM/256, CAP/128, NE), 256, 0, stream>>>(hid8, wt8, b2, list, wtok, kept, padoff, outb);
  combine_kernel<<<NT/4, 256, 0, stream>>>(outb, y);
}

// Round 14
// 392.808 us; speedup vs baseline: 1.3042x; 1.0212x over previous
//
#include <hip/hip_runtime.h>
#include <math.h>

#define NT   16384
#define DIM  1024
#define HID  2048
#define NE   16
#define CAP  8192

typedef __attribute__((ext_vector_type(4)))  float f32x4;
typedef __attribute__((ext_vector_type(16))) float f32x16;
typedef __attribute__((ext_vector_type(4)))  int   i32x4;
typedef __attribute__((ext_vector_type(8)))  int   i32x8;
typedef __attribute__((ext_vector_type(2)))  long long i64x2;

__device__ __forceinline__ unsigned pk4fp8(float a, float b, float c, float d){
  int lo  = __builtin_amdgcn_cvt_pk_fp8_f32(a, b, 0, false);
  int all = __builtin_amdgcn_cvt_pk_fp8_f32(c, d, lo, true);
  return (unsigned)all;
}
__device__ __forceinline__ unsigned char fp8one(float a){
  return (unsigned char)(__builtin_amdgcn_cvt_pk_fp8_f32(a, a, 0, false) & 0xff);
}
// OCP e4m3fn decode
__device__ __forceinline__ float fp8dec(unsigned b){
  unsigned e = (b >> 3) & 15u, m = b & 7u;
  union { unsigned u; float f; } c;
  if (e) { c.u = ((b & 0x80u) << 24) | ((e + 120u) << 23) | (m << 20); return c.f; }
  float mag = (float)m * 0.001953125f;
  return (b & 0x80u) ? -mag : mag;
}

#define GLOAD16(g, l) __builtin_amdgcn_global_load_lds( \
    (const __attribute__((address_space(1))) void*)(g), \
    (__attribute__((address_space(3))) void*)(l), 16, 0, 0)

// ---- fused: x -> fp8 (plain rows) + router logits/softmax/top2 + importance
__global__ __launch_bounds__(256) void convx_router_kernel(
    const float* __restrict__ x, const float* __restrict__ rw, const float* __restrict__ rb,
    unsigned* __restrict__ x8, int* __restrict__ tki, float* __restrict__ tkw,
    float* __restrict__ importance)
{
  __shared__ float sbuf[2][4][16];
  int tid = threadIdx.x;
  int lane = tid & 63, wid = tid >> 6;
  float W[64];
#pragma unroll
  for (int q=0;q<16;q++)
    *(float4*)(W + q*4) = ((const float4*)rw)[tid*16 + q];
  float rbv = rb[lane & 15];
  float impAcc = 0.f;
  int b0 = lane&1, b1=(lane>>1)&1, b2=(lane>>2)&1, b3=(lane>>3)&1;
#pragma unroll 1
  for (int t=0;t<8;++t){
    int tok = blockIdx.x*8 + t;
    float4 xv = ((const float4*)x)[tok*256 + tid];
    x8[tok*256 + tid] = pk4fp8(xv.x, xv.y, xv.z, xv.w);
    float p[16];
#pragma unroll
    for (int e=0;e<16;e++) p[e] = xv.x * W[e];
#pragma unroll
    for (int e=0;e<16;e++) p[e] += xv.y * W[16+e];
#pragma unroll
    for (int e=0;e<16;e++) p[e] += xv.z * W[32+e];
#pragma unroll
    for (int e=0;e<16;e++) p[e] += xv.w * W[48+e];
    float v8[8];
#pragma unroll
    for (int m=0;m<8;m++){
      float mine = b0 ? p[2*m+1] : p[2*m];
      float oth  = b0 ? p[2*m]   : p[2*m+1];
      v8[m] = mine + __shfl_xor(oth, 1, 64);
    }
    float v4a[4];
#pragma unroll
    for (int m=0;m<4;m++){
      float mine = b1 ? v8[2*m+1] : v8[2*m];
      float oth  = b1 ? v8[2*m]   : v8[2*m+1];
      v4a[m] = mine + __shfl_xor(oth, 2, 64);
    }
    float v2a[2];
#pragma unroll
    for (int m=0;m<2;m++){
      float mine = b2 ? v4a[2*m+1] : v4a[2*m];
      float oth  = b2 ? v4a[2*m]   : v4a[2*m+1];
      v2a[m] = mine + __shfl_xor(oth, 4, 64);
    }
    {
      float mine = b3 ? v2a[1] : v2a[0];
      float oth  = b3 ? v2a[0] : v2a[1];
      float v1 = mine + __shfl_xor(oth, 8, 64);
      v1 += __shfl_xor(v1, 16, 64);
      v1 += __shfl_xor(v1, 32, 64);
      if (lane < 16) sbuf[t&1][wid][lane] = v1;
    }
    __syncthreads();
    if (wid == 0){
      int e = lane & 15;
      float logit = sbuf[t&1][0][e] + sbuf[t&1][1][e] + sbuf[t&1][2][e] + sbuf[t&1][3][e] + rbv;
      float mx = logit;
#pragma unroll
      for (int d=1; d<16; d<<=1) mx = fmaxf(mx, __shfl_xor(mx, d, 64));
      float ex = __expf(logit - mx);
      float s = ex;
#pragma unroll
      for (int d=1; d<16; d<<=1) s += __shfl_xor(s, d, 64);
      float pe = ex / s;
      impAcc += pe;
      float v = pe; int idx = e;
#pragma unroll
      for (int d=1; d<16; d<<=1){
        float ov = __shfl_xor(v, d, 64);
        int   oi = __shfl_xor(idx, d, 64);
        bool bet = (ov > v) || (ov == v && oi < idx);
        v = bet ? ov : v; idx = bet ? oi : idx;
      }
      float vt1 = v; int i1 = idx;
      float pm = (e == i1) ? -1.f : pe;
      v = pm; idx = e;
#pragma unroll
      for (int d=1; d<16; d<<=1){
        float ov = __shfl_xor(v, d, 64);
        int   oi = __shfl_xor(idx, d, 64);
        bool bet = (ov > v) || (ov == v && oi < idx);
        v = bet ? ov : v; idx = bet ? oi : idx;
      }
      if (lane == 0){
        tki[2*tok] = i1; tki[2*tok+1] = idx;
        tkw[2*tok] = vt1; tkw[2*tok+1] = v;
      }
    }
  }
  if (wid == 0 && lane < 16) atomicAdd(&importance[lane], impAcc);
}

// ---------------- w [E][K][N] f32 -> wt8 [E][N][K] fp8 x16 (plain) ----------
__global__ __launch_bounds__(256) void prepw_kernel(const float* __restrict__ w,
                                                    unsigned char* __restrict__ wt8,
                                                    int K, int N, float scale){
  __shared__ float T[64][65];
  int e = blockIdx.z;
  int n0 = blockIdx.x*64, k0 = blockIdx.y*64;
  const float* we = w + (size_t)e*K*N;
  unsigned char* oe = wt8 + (size_t)e*K*N;
  int tid = threadIdx.x;
  int rr = tid >> 4, c4 = tid & 15;
#pragma unroll
  for (int p = 0; p < 4; ++p){
    int r = rr + p*16;
    float4 v = *(const float4*)(we + (size_t)(k0 + r)*N + n0 + c4*4);
    T[r][c4*4+0] = v.x*scale; T[r][c4*4+1] = v.y*scale;
    T[r][c4*4+2] = v.z*scale; T[r][c4*4+3] = v.w*scale;
  }
  __syncthreads();
#pragma unroll
  for (int p = 0; p < 4; ++p){
    int n = rr + p*16;
    unsigned u = pk4fp8(T[c4*4+0][n], T[c4*4+1][n], T[c4*4+2][n], T[c4*4+3][n]);
    *(unsigned*)(oe + (size_t)(n0 + n)*K + k0 + c4*4) = u;
  }
}

// ---------------- per-expert ordered lists (ballot scan) --------------------
__global__ __launch_bounds__(1024) void build_lists_kernel(
    const int* __restrict__ tki, const float* __restrict__ tkw,
    int* __restrict__ list, float* __restrict__ wtok, int* __restrict__ keptArr,
    int* __restrict__ counts)
{
  __shared__ int swsum[16];
  int e = blockIdx.x;
  int tid = threadIdx.x, wid = tid >> 6, lane = tid & 63;
  int base = 0;
  for (int c = 0; c < NT/1024; ++c){
    int t = c*1024 + tid;
    int i1 = tki[2*t], i2 = tki[2*t+1];
    bool m = (i1==e) || (i2==e);
    unsigned long long bal = __ballot(m);
    int inw = __popcll(bal & ((1ull << lane) - 1ull));
    if (lane == 0) swsum[wid] = __popcll(bal);
    __syncthreads();
    int pre = 0, tot = 0;
#pragma unroll
    for (int w = 0; w < 16; ++w){
      int v = swsum[w];
      tot += v;
      if (w < wid) pre += v;
    }
    int rank = base + pre + inw;
    if (m && rank < CAP){
      list[e*CAP + rank] = t;
      wtok[e*CAP + rank] = (i1==e) ? tkw[2*t] : -tkw[2*t+1];
    }
    base += tot;
    __syncthreads();
  }
  if (tid==0){ counts[e] = base; keptArr[e] = min(base, CAP); }
}

// ---------------- aux loss + padded (128) row offsets -----------------------
__global__ void finalize_kernel(const int* __restrict__ counts, const float* __restrict__ importance,
                                const int* __restrict__ keptArr, int* __restrict__ padOff,
                                float* __restrict__ auxOut)
{
  if (threadIdx.x == 0 && blockIdx.x == 0){
    float bal = 0.f, il = 0.f;
    int po = 0;
    padOff[0] = 0;
    for (int e=0;e<16;e++){
      float im = importance[e];
      float cf = (float)counts[e];
      bal += (im * (1.f/NT)) * (cf * (1.f/NT));
      il  += im*im;
      po  += ((keptArr[e] + 127) >> 7) << 7;
      padOff[e+1] = po;
    }
    auxOut[0] = bal * 16.f + il * (1.f/16.f);
  }
}

// ===== 128x128 MX-fp8 GEMM, 32x32x64 scaled MFMA, BK=64 =====================
// R14 = R12 skeleton (3 x 16KB counted buffers, vmcnt(4) ledger, 3 blocks/CU)
// with the ONLY change being the granule permutation p(r) = (r>>1)&3
// (was r&3). Bank enumeration: per 16-lane frag-read group, bank-starts
// {0,4,8,...,28} each hit exactly 2x = conflict-free (m136: 2-way is free);
// old perm gave starts {0,8,20,28} each 4x = 1.58x tax (~390cy/block-iter,
// the dominant LDS-pipe cost identified in R13's post-mortem).
// Staging: linear LDS dest, source granule u ^ p(row) (within-row, coalesced);
// frag read XORs the same p(row) -> involution-consistent (rule 21).
// A-frag: lane l -> row l&31, 32B at k=(l>>5)*32. C/D: col=lane&31,
// row=(q&3)+8*(q>>2)+4*(lane>>5) [m74/m101]. Scales: A x1(127), B x2^-4(123).

#define SETUP_PTRS(SRC_A_EXPR, SRC_B_EXPR) \
  const unsigned char* pA[2]; const unsigned char* pB[2]; \
  _Pragma("unroll") \
  for (int l=0; l<2; ++l){ \
    int row = l*64 + (tid >> 2); \
    int u = tid & 3; \
    int koff = ((u ^ ((row>>1) & 3)) << 4); \
    pA[l] = (SRC_A_EXPR) + koff; \
    pB[l] = (SRC_B_EXPR) + koff; \
  }

#define STAGE4(b) do{ \
  GLOAD16(pA[0], lds + (b)*16384 + tid*16); \
  GLOAD16(pA[1], lds + (b)*16384 + 4096 + tid*16); \
  GLOAD16(pB[0], lds + (b)*16384 + 8192 + tid*16); \
  GLOAD16(pB[1], lds + (b)*16384 + 12288 + tid*16); \
  pA[0]+=64; pA[1]+=64; pB[0]+=64; pB[1]+=64; }while(0)

#define RDFRAG(dst, base) do{ \
  union { i32x8 v; i32x4 h[2]; } _u; \
  _u.h[0] = *(const i32x4*)(lds + (base)); \
  _u.h[1] = *(const i32x4*)(lds + ((base) ^ 16)); \
  dst = _u.v; }while(0)

#define KLOOP(NT_) \
  STAGE4(0); \
  STAGE4(1); \
  asm volatile("s_waitcnt vmcnt(4)" ::: "memory"); \
  __builtin_amdgcn_s_barrier(); \
  { int cb = 0, sb = 2; \
    for (int t = 0; t < (NT_); ++t){ \
      if (t+2 < (NT_)) STAGE4(sb); \
      int cbase = cb*16384; \
      i32x8 afr[2], bfr[2]; \
      RDFRAG(afr[0], cbase + offA0); \
      RDFRAG(afr[1], cbase + offA1); \
      RDFRAG(bfr[0], cbase + offB0); \
      RDFRAG(bfr[1], cbase + offB1); \
      __builtin_amdgcn_s_setprio(1); \
      acc[0][0] = __builtin_amdgcn_mfma_scale_f32_32x32x64_f8f6f4(afr[0], bfr[0], acc[0][0], 0,0, 0,127, 0,123); \
      acc[0][1] = __builtin_amdgcn_mfma_scale_f32_32x32x64_f8f6f4(afr[0], bfr[1], acc[0][1], 0,0, 0,127, 0,123); \
      acc[1][0] = __builtin_amdgcn_mfma_scale_f32_32x32x64_f8f6f4(afr[1], bfr[0], acc[1][0], 0,0, 0,127, 0,123); \
      acc[1][1] = __builtin_amdgcn_mfma_scale_f32_32x32x64_f8f6f4(afr[1], bfr[1], acc[1][1], 0,0, 0,127, 0,123); \
      __builtin_amdgcn_s_setprio(0); \
      if (t+1 < (NT_)){ \
        if (t+2 < (NT_)) asm volatile("s_waitcnt vmcnt(4)" ::: "memory"); \
        else             asm volatile("s_waitcnt vmcnt(0)" ::: "memory"); \
      } \
      __builtin_amdgcn_s_barrier(); \
      cb = (cb==2)?0:cb+1; sb = (sb==2)?0:sb+1; \
    } \
  }

// ---------------- GEMM1: hid8 = gelu(gather(x8) @ w1t8^T + b1) --------------
__global__ __launch_bounds__(256, 3) void gemm1_kernel(
    const unsigned char* __restrict__ x8, const unsigned char* __restrict__ w1t8,
    const float* __restrict__ b1, const int* __restrict__ list,
    const int* __restrict__ keptArr, const int* __restrict__ padOff,
    unsigned char* __restrict__ hid8)
{
  __shared__ unsigned char lds[49152];   // 3 x 16KB; epilogue reuses [0,16K)
  int e = blockIdx.z;
  int kept = keptArr[e];
  int mt = blockIdx.y;
  if (mt*128 >= kept) return;
  int n0 = blockIdx.x * 128;

  const unsigned char* Wg = w1t8 + (size_t)e*DIM*HID;
  const int* lst = list + e*CAP;
  int tid = threadIdx.x;
  int lane = tid & 63, wv = tid >> 6;
  int wr = wv >> 1, wc = wv & 1;
  int l31 = lane & 31, kh = lane >> 5;
  int swz = ((kh*2) ^ ((l31>>1) & 3)) << 4;
  int offA0 = (wr*64 + l31)*64 + swz;
  int offA1 = offA0 + 32*64;
  int offB0 = 8192 + (wc*64 + l31)*64 + swz;
  int offB1 = offB0 + 32*64;

  SETUP_PTRS(x8 + (size_t)lst[min(mt*128 + row, kept-1)]*DIM,
             Wg + (size_t)(n0 + row)*DIM)

  f32x16 acc[2][2];
#pragma unroll
  for (int i=0;i<2;i++)
#pragma unroll
    for (int j=0;j<2;j++)
#pragma unroll
      for (int q=0;q<16;q++) acc[i][j][q] = 0.f;

  KLOOP(DIM/64)   // 16

  __builtin_amdgcn_s_barrier();   // all K-loop LDS reads done before reuse

  // epilogue: bias+gelu -> fp8, LDS repack, coalesced 16B stores
  const float* b1e = b1 + (size_t)e*HID;
#pragma unroll
  for (int i=0;i<2;i++){
#pragma unroll
    for (int j=0;j<2;j++){
      int c = wc*64 + j*32 + l31;
      float bias = b1e[n0 + c];
#pragma unroll
      for (int q=0;q<16;q++){
        int lrow = wr*64 + i*32 + (q&3) + 8*(q>>2) + 4*kh;
        float v = acc[i][j][q] + bias;
        float s = 1.f/(1.f + __expf(-1.702f*v));   // sigmoid-approx GELU
        lds[lrow*128 + (c ^ ((lrow&7)<<4))] = fp8one(v*s);
      }
    }
  }
  __builtin_amdgcn_s_barrier();
  size_t rowBase = (size_t)padOff[e] + (size_t)mt*128;
#pragma unroll
  for (int w=0; w<4; ++w){
    int idx = w*256 + tid;
    int row = idx >> 3, u = idx & 7;
    *(i64x2*)(hid8 + (rowBase + row)*HID + n0 + u*16) =
        *(const i64x2*)(lds + row*128 + ((u*16) ^ ((row&7)<<4)));
  }
}

// ---------------- GEMM2: outb[k][tok] = fp8( w * (hid8 @ w2t8^T + b2) ) -----
__global__ __launch_bounds__(256, 3) void gemm2_kernel(
    const unsigned char* __restrict__ hid8, const unsigned char* __restrict__ w2t8,
    const float* __restrict__ b2, const int* __restrict__ list,
    const float* __restrict__ wtok, const int* __restrict__ keptArr,
    const int* __restrict__ padOff, unsigned char* __restrict__ outb)
{
  __shared__ unsigned char lds[49152];
  __shared__ int   s_tk[128];
  __shared__ float s_wv[128];
  int e = blockIdx.z;
  int kept = keptArr[e];
  int mt = blockIdx.y;
  if (mt*128 >= kept) return;
  int n0 = blockIdx.x * 128;

  const unsigned char* Wg = w2t8 + (size_t)e*HID*DIM;
  const unsigned char* hb = hid8 + ((size_t)padOff[e] + (size_t)mt*128)*HID;
  const int*   lst = list + e*CAP;
  const float* wt  = wtok + e*CAP;
  int tid = threadIdx.x;
  int lane = tid & 63, wv = tid >> 6;
  int wr = wv >> 1, wc = wv & 1;
  int l31 = lane & 31, kh = lane >> 5;
  int swz = ((kh*2) ^ ((l31>>1) & 3)) << 4;
  int offA0 = (wr*64 + l31)*64 + swz;
  int offA1 = offA0 + 32*64;
  int offB0 = 8192 + (wc*64 + l31)*64 + swz;
  int offB1 = offB0 + 32*64;

  if (tid < 128){
    int m = mt*128 + tid;
    if (m < kept){
      float we = wt[m];
      s_tk[tid] = lst[m] | ((we < 0.f) ? (1<<30) : 0);
      s_wv[tid] = fabsf(we);
    } else { s_tk[tid] = -1; s_wv[tid] = 0.f; }
  }

  SETUP_PTRS(hb + (size_t)row*HID,
             Wg + (size_t)(n0 + row)*HID)

  f32x16 acc[2][2];
#pragma unroll
  for (int i=0;i<2;i++)
#pragma unroll
    for (int j=0;j<2;j++)
#pragma unroll
      for (int q=0;q<16;q++) acc[i][j][q] = 0.f;

  KLOOP(HID/64)   // 32

  __builtin_amdgcn_s_barrier();

  // epilogue: w*(acc + b2) -> fp8, repack via LDS, 16B stores to outb
  const float* b2e = b2 + (size_t)e*DIM;
#pragma unroll
  for (int i=0;i<2;i++){
#pragma unroll
    for (int j=0;j<2;j++){
      int c = wc*64 + j*32 + l31;
      float bias = b2e[n0 + c];
#pragma unroll
      for (int q=0;q<16;q++){
        int lrow = wr*64 + i*32 + (q&3) + 8*(q>>2) + 4*kh;
        float v = (acc[i][j][q] + bias) * s_wv[lrow];
        lds[lrow*128 + (c ^ ((lrow&7)<<4))] = fp8one(v);
      }
    }
  }
  __builtin_amdgcn_s_barrier();
#pragma unroll
  for (int w=0; w<4; ++w){
    int idx = w*256 + tid;
    int row = idx >> 3, u = idx & 7;
    int tk = s_tk[row];
    if (tk >= 0){
      int tok = tk & 0xffff, k = tk >> 30;
      *(i64x2*)(outb + ((size_t)(k*NT + tok))*DIM + n0 + u*16) =
          *(const i64x2*)(lds + row*128 + ((u*16) ^ ((row&7)<<4)));
    }
  }
}

// ---------------- combine: y = dec(outb[0][t]) + dec(outb[1][t]) ------------
__global__ __launch_bounds__(256) void combine_kernel(const unsigned char* __restrict__ outb,
                                                      float* __restrict__ y)
{
  int wid = threadIdx.x >> 6, lane = threadIdx.x & 63;
  int t = blockIdx.x*4 + wid;
  const uint4 a = *(const uint4*)(outb + (size_t)t*DIM + lane*16);
  const uint4 b = *(const uint4*)(outb + (size_t)(NT + t)*DIM + lane*16);
  float4* yo = (float4*)(y + (size_t)t*DIM + lane*16);
  unsigned ad[4] = {a.x, a.y, a.z, a.w};
  unsigned bd[4] = {b.x, b.y, b.z, b.w};
#pragma unroll
  for (int d=0; d<4; ++d){
    float4 o;
    o.x = fp8dec(ad[d] & 0xff)        + fp8dec(bd[d] & 0xff);
    o.y = fp8dec((ad[d]>>8) & 0xff)   + fp8dec((bd[d]>>8) & 0xff);
    o.z = fp8dec((ad[d]>>16) & 0xff)  + fp8dec((bd[d]>>16) & 0xff);
    o.w = fp8dec((ad[d]>>24) & 0xff)  + fp8dec((bd[d]>>24) & 0xff);
    yo[d] = o;
  }
}

// ---------------- launch ----------------------------------------------------
extern "C" void kernel_launch(void* const* d_in, const int* in_sizes, int n_in,
                              void* d_out, int out_size, void* d_ws, size_t ws_size,
                              hipStream_t stream)
{
  (void)in_sizes; (void)n_in; (void)ws_size; (void)out_size;
  const float* x  = (const float*)d_in[0];
  const float* rw = (const float*)d_in[1];
  const float* rb = (const float*)d_in[2];
  const float* w1 = (const float*)d_in[3];
  const float* b1 = (const float*)d_in[4];
  const float* w2 = (const float*)d_in[5];
  const float* b2 = (const float*)d_in[6];
  float* y = (float*)d_out;

  char* ws = (char*)d_ws;
  int*   counts = (int*)(ws + 0);
  int*   kept   = (int*)(ws + 64);
  float* imp    = (float*)(ws + 128);
  int*   padoff = (int*)(ws + 192);
  int*   list   = (int*)(ws + 0x1000);     // 512 KiB
  float* wtok   = (float*)(ws + 0x81000);  // 512 KiB
  int*   tki    = (int*)(ws + 0x101000);   // 128 KiB
  float* tkw    = (float*)(ws + 0x121000); // 128 KiB
  unsigned char* wt8  = (unsigned char*)(ws + 0x180000);   // 32 MiB (w1 then w2)
  unsigned char* hid8 = (unsigned char*)(ws + 0x2180000);  // 68 MiB (34816 x 2048)
  unsigned char* big  = (unsigned char*)(ws + 0x6580000);  // 32 MiB: x8 then outb
  unsigned char* x8   = big;                               // 16 MiB, dead after gemm1
  unsigned char* outb = big;                               // 32 MiB, overlays x8
  // total = 0x8580000 = 139.9 MiB

  hipMemsetAsync(ws, 0, 4096, stream);

  convx_router_kernel<<<NT/8, 256, 0, stream>>>(x, rw, rb, (unsigned*)x8, tki, tkw, imp);
  build_lists_kernel<<<16, 1024, 0, stream>>>(tki, tkw, list, wtok, kept, counts);
  finalize_kernel<<<1, 64, 0, stream>>>(counts, imp, kept, padoff, y + (size_t)NT*DIM);
  prepw_kernel<<<dim3(HID/64, DIM/64, NE), 256, 0, stream>>>(w1, wt8, DIM, HID, 16.f);
  gemm1_kernel<<<dim3(HID/128, CAP/128, NE), 256, 0, stream>>>(x8, wt8, b1, list, kept, padoff, hid8);
  // x8 now dead -> outb takes the region
  hipMemsetAsync(outb, 0, (size_t)2*NT*DIM, stream);
  prepw_kernel<<<dim3(DIM/64, HID/64, NE), 256, 0, stream>>>(w2, wt8, HID, DIM, 16.f);
  gemm2_kernel<<<dim3(DIM/128, CAP/128, NE), 256, 0, stream>>>(hid8, wt8, b2, list, wtok, kept, padoff, outb);
  combine_kernel<<<NT/4, 256, 0, stream>>>(outb, y);
}